// Round 3
// baseline (590.826 us; speedup 1.0000x reference)
//
#include <hip/hip_runtime.h>

#define N_NODES 50000
#define N_EDGES 800000

typedef __bf16 bf16x8 __attribute__((ext_vector_type(8)));
typedef unsigned short ushort8 __attribute__((ext_vector_type(8)));
typedef float f32x4 __attribute__((ext_vector_type(4)));

__device__ __forceinline__ float lane_bcast(float v, int l) {
    return __builtin_bit_cast(float, __builtin_amdgcn_readlane(__builtin_bit_cast(int, v), l));
}

// fp32 -> bf16 bits, round-to-nearest-even
__device__ __forceinline__ unsigned short f2bf(float f) {
    unsigned u = __builtin_bit_cast(unsigned, f);
    u += 0x7fffu + ((u >> 16) & 1u);
    return (unsigned short)(u >> 16);
}

// ---------------------------------------------------------------------------
// CSR build: histogram -> exclusive scan -> scatter (dst-sorted edge perm,
// plus src gathered into sorted order so the gather kernel reads contiguously)
// ---------------------------------------------------------------------------
__global__ __launch_bounds__(256) void csr_hist(const int* __restrict__ dstp,
                                                int* __restrict__ cnt) {
    for (int e = blockIdx.x * blockDim.x + threadIdx.x; e < N_EDGES;
         e += gridDim.x * blockDim.x)
        atomicAdd(&cnt[dstp[e]], 1);
}

__global__ __launch_bounds__(1024) void csr_scan(const int* __restrict__ cnt,
                                                 int* __restrict__ offs) {
    __shared__ int sm[1024];
    const int t = threadIdx.x;
    const int CH = (N_NODES + 1023) / 1024;          // 49
    const int lo = t * CH;
    const int hi = (lo + CH < N_NODES) ? lo + CH : N_NODES;
    int s = 0;
    for (int i = lo; i < hi; ++i) s += cnt[i];
    sm[t] = s;
    __syncthreads();
    for (int off = 1; off < 1024; off <<= 1) {
        int v = (t >= off) ? sm[t - off] : 0;
        __syncthreads();
        sm[t] += v;
        __syncthreads();
    }
    int run = (t == 0) ? 0 : sm[t - 1];
    for (int i = lo; i < hi; ++i) { offs[i] = run; run += cnt[i]; }
    if (t == 1023) offs[N_NODES] = sm[1023];
}

__global__ __launch_bounds__(256) void csr_scatter(
    const int* __restrict__ srcp, const int* __restrict__ dstp,
    const int* __restrict__ offs, int* __restrict__ runc,
    int* __restrict__ perm, int* __restrict__ ssrc) {
    for (int e = blockIdx.x * blockDim.x + threadIdx.x; e < N_EDGES;
         e += gridDim.x * blockDim.x) {
        const int d = dstp[e];
        const int p = offs[d] + atomicAdd(&runc[d], 1);
        perm[p] = e;
        ssrc[p] = srcp[e];
    }
}

// ---------------------------------------------------------------------------
// Gather kernel (MFMA, atomic-free): one wave per node. Walk the node's
// incoming edges in 16-edge tiles; msg = relu(x[src] + ea@W + b) via
// mfma_f32_16x16x32_bf16 (A: m=lane&15, k=quad*8+j; D: col=lane&15,
// row=quad*4+reg); segmented sum entirely in registers + shfl_xor across
// quads; one coalesced 256B store of agg[n]. Padded rows load zero A-frags.
// ---------------------------------------------------------------------------
__global__ __launch_bounds__(256) void gine_gather_mfma(
    const float* __restrict__ xin,   // [N,64]
    const float* __restrict__ ea,    // [E,32]
    const int*   __restrict__ perm,  // [E] dst-sorted edge ids
    const int*   __restrict__ ssrc,  // [E] src in sorted order
    const int*   __restrict__ offs,  // [N+1]
    const float* __restrict__ linW,  // [32,64]
    const float* __restrict__ linB,  // [64]
    float*       __restrict__ agg)   // [N,64]
{
    const int lane   = threadIdx.x & 63;
    const int gwave  = (blockIdx.x * blockDim.x + threadIdx.x) >> 6;
    const int nwaves = (gridDim.x * blockDim.x) >> 6;
    const int row    = lane & 15;
    const int quad   = lane >> 4;

    // B fragments: wf[t][j] = W[quad*8+j][t*16+row]
    bf16x8 wf[4];
#pragma unroll
    for (int t = 0; t < 4; ++t) {
        ushort8 us = {0, 0, 0, 0, 0, 0, 0, 0};
#pragma unroll
        for (int j = 0; j < 8; ++j)
            us[j] = f2bf(linW[(quad * 8 + j) * 64 + t * 16 + row]);
        wf[t] = __builtin_bit_cast(bf16x8, us);
    }
    float bias[4];
#pragma unroll
    for (int t = 0; t < 4; ++t) bias[t] = linB[t * 16 + row];

    for (int n = gwave; n < N_NODES; n += nwaves) {
        const int start = offs[n];
        const int end   = offs[n + 1];

        float s0 = 0.f, s1 = 0.f, s2 = 0.f, s3 = 0.f;

        for (int base = start; base < end; base += 16) {
            // A fragment for edge slot base+row (zero-padded past end)
            ushort8 ua = {0, 0, 0, 0, 0, 0, 0, 0};
            const int eidx = base + row;
            if (eidx < end) {
                const int e = perm[eidx];
                const float* ap = ea + (size_t)e * 32 + quad * 8;
                const float4 a0 = *(const float4*)ap;
                const float4 a1 = *(const float4*)(ap + 4);
                ua[0] = f2bf(a0.x); ua[1] = f2bf(a0.y);
                ua[2] = f2bf(a0.z); ua[3] = f2bf(a0.w);
                ua[4] = f2bf(a1.x); ua[5] = f2bf(a1.y);
                ua[6] = f2bf(a1.z); ua[7] = f2bf(a1.w);
            }
            const bf16x8 af = __builtin_bit_cast(bf16x8, ua);

            f32x4 acc[4];
#pragma unroll
            for (int t = 0; t < 4; ++t)
                acc[t] = __builtin_amdgcn_mfma_f32_16x16x32_bf16(
                    af, wf[t], (f32x4){0.f, 0.f, 0.f, 0.f}, 0, 0, 0);

#pragma unroll
            for (int r = 0; r < 4; ++r) {
                const int ei = base + quad * 4 + r;
                if (ei < end) {
                    const int s = ssrc[ei];
                    const float* xrow = xin + (size_t)s * 64;
                    s0 += fmaxf(xrow[ 0 + row] + bias[0] + acc[0][r], 0.f);
                    s1 += fmaxf(xrow[16 + row] + bias[1] + acc[1][r], 0.f);
                    s2 += fmaxf(xrow[32 + row] + bias[2] + acc[2][r], 0.f);
                    s3 += fmaxf(xrow[48 + row] + bias[3] + acc[3][r], 0.f);
                }
            }
        }

        // reduce across the 4 quads (each holds a partial over its edges)
        s0 += __shfl_xor(s0, 16); s0 += __shfl_xor(s0, 32);
        s1 += __shfl_xor(s1, 16); s1 += __shfl_xor(s1, 32);
        s2 += __shfl_xor(s2, 16); s2 += __shfl_xor(s2, 32);
        s3 += __shfl_xor(s3, 16); s3 += __shfl_xor(s3, 32);

        const float v = (quad == 0) ? s0 : (quad == 1) ? s1
                       : (quad == 2) ? s2 : s3;   // lane = quad*16+row ↔ channel
        agg[(size_t)n * 64 + lane] = v;
    }
}

// ---------------------------------------------------------------------------
// Node kernel (conv1): h = x + agg; h = relu(h@w1+b1); h = relu(h@w2+b2).
// ---------------------------------------------------------------------------
__global__ __launch_bounds__(256) void gine_node(
    const float* __restrict__ xin, const float* __restrict__ agg,
    const float* __restrict__ w1, const float* __restrict__ b1,
    const float* __restrict__ w2, const float* __restrict__ b2,
    float* __restrict__ hout)
{
    const int lane   = threadIdx.x & 63;
    const int gwave  = (blockIdx.x * blockDim.x + threadIdx.x) >> 6;
    const int nwaves = (gridDim.x * blockDim.x) >> 6;

    float w1c[64], w2c[64];
#pragma unroll
    for (int k = 0; k < 64; ++k) w1c[k] = w1[k * 64 + lane];
#pragma unroll
    for (int k = 0; k < 64; ++k) w2c[k] = w2[k * 64 + lane];
    const float bb1 = b1[lane], bb2 = b2[lane];

    for (int n = gwave; n < N_NODES; n += nwaves) {
        const float h = xin[n * 64 + lane] + agg[n * 64 + lane];

        float t0 = bb1, t1 = 0.f, t2 = 0.f, t3 = 0.f;
#pragma unroll
        for (int k = 0; k < 64; k += 4) {
            t0 = fmaf(lane_bcast(h, k + 0), w1c[k + 0], t0);
            t1 = fmaf(lane_bcast(h, k + 1), w1c[k + 1], t1);
            t2 = fmaf(lane_bcast(h, k + 2), w1c[k + 2], t2);
            t3 = fmaf(lane_bcast(h, k + 3), w1c[k + 3], t3);
        }
        const float t = fmaxf((t0 + t1) + (t2 + t3), 0.0f);

        float u0 = bb2, u1 = 0.f, u2 = 0.f, u3 = 0.f;
#pragma unroll
        for (int k = 0; k < 64; k += 4) {
            u0 = fmaf(lane_bcast(t, k + 0), w2c[k + 0], u0);
            u1 = fmaf(lane_bcast(t, k + 1), w2c[k + 1], u1);
            u2 = fmaf(lane_bcast(t, k + 2), w2c[k + 2], u2);
            u3 = fmaf(lane_bcast(t, k + 3), w2c[k + 3], u3);
        }
        hout[n * 64 + lane] = fmaxf((u0 + u1) + (u2 + u3), 0.0f);
    }
}

// ---------------------------------------------------------------------------
// Node kernel (conv2 + head)
// ---------------------------------------------------------------------------
__global__ __launch_bounds__(256) void gine_node_head(
    const float* __restrict__ xin, const float* __restrict__ agg,
    const float* __restrict__ w1, const float* __restrict__ b1,
    const float* __restrict__ w2, const float* __restrict__ b2,
    const float* __restrict__ hw, const float* __restrict__ hb,
    float* __restrict__ outp)
{
    const int lane   = threadIdx.x & 63;
    const int gwave  = (blockIdx.x * blockDim.x + threadIdx.x) >> 6;
    const int nwaves = (gridDim.x * blockDim.x) >> 6;

    float w1c[64], w2c[64], hwc[64];
#pragma unroll
    for (int k = 0; k < 64; ++k) w1c[k] = w1[k * 64 + lane];
#pragma unroll
    for (int k = 0; k < 64; ++k) w2c[k] = w2[k * 64 + lane];
#pragma unroll
    for (int k = 0; k < 64; ++k) hwc[k] = hw[k * 32 + (lane & 31)];
    const float bb1 = b1[lane], bb2 = b2[lane];
    const float hbb = hb[lane & 31];

    for (int n = gwave; n < N_NODES; n += nwaves) {
        const float h = xin[n * 64 + lane] + agg[n * 64 + lane];

        float t0 = bb1, t1 = 0.f, t2 = 0.f, t3 = 0.f;
#pragma unroll
        for (int k = 0; k < 64; k += 4) {
            t0 = fmaf(lane_bcast(h, k + 0), w1c[k + 0], t0);
            t1 = fmaf(lane_bcast(h, k + 1), w1c[k + 1], t1);
            t2 = fmaf(lane_bcast(h, k + 2), w1c[k + 2], t2);
            t3 = fmaf(lane_bcast(h, k + 3), w1c[k + 3], t3);
        }
        const float t = fmaxf((t0 + t1) + (t2 + t3), 0.0f);

        float u0 = bb2, u1 = 0.f, u2 = 0.f, u3 = 0.f;
#pragma unroll
        for (int k = 0; k < 64; k += 4) {
            u0 = fmaf(lane_bcast(t, k + 0), w2c[k + 0], u0);
            u1 = fmaf(lane_bcast(t, k + 1), w2c[k + 1], u1);
            u2 = fmaf(lane_bcast(t, k + 2), w2c[k + 2], u2);
            u3 = fmaf(lane_bcast(t, k + 3), w2c[k + 3], u3);
        }
        const float u = fmaxf((u0 + u1) + (u2 + u3), 0.0f);

        float o0 = hbb, o1 = 0.f, o2 = 0.f, o3 = 0.f;
#pragma unroll
        for (int k = 0; k < 64; k += 4) {
            o0 = fmaf(lane_bcast(u, k + 0), hwc[k + 0], o0);
            o1 = fmaf(lane_bcast(u, k + 1), hwc[k + 1], o1);
            o2 = fmaf(lane_bcast(u, k + 2), hwc[k + 2], o2);
            o3 = fmaf(lane_bcast(u, k + 3), hwc[k + 3], o3);
        }
        if (lane < 32) outp[n * 32 + lane] = (o0 + o1) + (o2 + o3);
    }
}

extern "C" void kernel_launch(void* const* d_in, const int* in_sizes, int n_in,
                              void* d_out, int out_size, void* d_ws, size_t ws_size,
                              hipStream_t stream) {
    const float* x     = (const float*)d_in[0];
    const float* ea    = (const float*)d_in[1];
    const int*   ei    = (const int*)  d_in[2];
    const float* c1lw  = (const float*)d_in[3];
    const float* c1lb  = (const float*)d_in[4];
    const float* c1w1  = (const float*)d_in[5];
    const float* c1b1  = (const float*)d_in[6];
    const float* c1w2  = (const float*)d_in[7];
    const float* c1b2  = (const float*)d_in[8];
    const float* c2lw  = (const float*)d_in[9];
    const float* c2lb  = (const float*)d_in[10];
    const float* c2w1  = (const float*)d_in[11];
    const float* c2b1  = (const float*)d_in[12];
    const float* c2w2  = (const float*)d_in[13];
    const float* c2b2  = (const float*)d_in[14];
    const float* hw    = (const float*)d_in[15];
    const float* hb    = (const float*)d_in[16];

    const int* srcp = ei;
    const int* dstp = ei + N_EDGES;

    // workspace layout
    float* agg  = (float*)d_ws;                               // [N,64]
    float* h1   = agg + (size_t)N_NODES * 64;                 // [N,64]
    int*   cnt  = (int*)(h1 + (size_t)N_NODES * 64);          // [N]
    int*   offs = cnt + N_NODES;                              // [N+1]
    int*   runc = offs + (N_NODES + 1);                       // [N]
    int*   perm = runc + N_NODES;                             // [E]
    int*   ssrc = perm + N_EDGES;                             // [E]
    float* outp = (float*)d_out;                              // [N,32]

    // ---- CSR build (shared by both convs) ----
    hipMemsetAsync(cnt,  0, N_NODES * sizeof(int), stream);
    hipMemsetAsync(runc, 0, N_NODES * sizeof(int), stream);
    hipLaunchKernelGGL(csr_hist,    dim3(1024), dim3(256),  0, stream, dstp, cnt);
    hipLaunchKernelGGL(csr_scan,    dim3(1),    dim3(1024), 0, stream, cnt, offs);
    hipLaunchKernelGGL(csr_scatter, dim3(1024), dim3(256),  0, stream,
                       srcp, dstp, offs, runc, perm, ssrc);

    // ---- conv1 ----
    hipLaunchKernelGGL(gine_gather_mfma, dim3(2048), dim3(256), 0, stream,
                       x, ea, perm, ssrc, offs, c1lw, c1lb, agg);
    hipLaunchKernelGGL(gine_node, dim3(1024), dim3(256), 0, stream,
                       x, agg, c1w1, c1b1, c1w2, c1b2, h1);

    // ---- conv2 + head ----
    hipLaunchKernelGGL(gine_gather_mfma, dim3(2048), dim3(256), 0, stream,
                       h1, ea, perm, ssrc, offs, c2lw, c2lb, agg);
    hipLaunchKernelGGL(gine_node_head, dim3(1024), dim3(256), 0, stream,
                       h1, agg, c2w1, c2b1, c2w2, c2b2, hw, hb, outp);
}

// Round 4
// 505.040 us; speedup vs baseline: 1.1699x; 1.1699x over previous
//
#include <hip/hip_runtime.h>

#define N_NODES 50000
#define N_EDGES 800000

typedef __bf16 bf16x8 __attribute__((ext_vector_type(8)));
typedef unsigned short ushort8 __attribute__((ext_vector_type(8)));
typedef float f32x4 __attribute__((ext_vector_type(4)));

__device__ __forceinline__ unsigned short f2bf(float f) {
    unsigned u = __builtin_bit_cast(unsigned, f);
    u += 0x7fffu + ((u >> 16) & 1u);
    return (unsigned short)(u >> 16);
}

// ---------------------------------------------------------------------------
// CSR build: histogram -> scan -> scatter.
// Primary scatter also permutes+casts ea into dst-sorted bf16 (ea_s).
// ---------------------------------------------------------------------------
__global__ __launch_bounds__(256) void csr_hist(const int* __restrict__ dstp,
                                                int* __restrict__ cnt) {
    for (int e = blockIdx.x * blockDim.x + threadIdx.x; e < N_EDGES;
         e += gridDim.x * blockDim.x)
        atomicAdd(&cnt[dstp[e]], 1);
}

__global__ __launch_bounds__(1024) void csr_scan(const int* __restrict__ cnt,
                                                 int* __restrict__ offs) {
    __shared__ int sm[1024];
    const int t = threadIdx.x;
    const int CH = (N_NODES + 1023) / 1024;          // 49
    const int lo = t * CH;
    const int hi = (lo + CH < N_NODES) ? lo + CH : N_NODES;
    int s = 0;
    for (int i = lo; i < hi; ++i) s += cnt[i];
    sm[t] = s;
    __syncthreads();
    for (int off = 1; off < 1024; off <<= 1) {
        int v = (t >= off) ? sm[t - off] : 0;
        __syncthreads();
        sm[t] += v;
        __syncthreads();
    }
    int run = (t == 0) ? 0 : sm[t - 1];
    for (int i = lo; i < hi; ++i) { offs[i] = run; run += cnt[i]; }
    if (t == 1023) offs[N_NODES] = sm[1023];
}

// Primary: ssrc[p]=src, ea_s[p]=bf16(ea[e])  (dst-sorted, coalesced reads)
__global__ __launch_bounds__(256) void csr_scatter_ea(
    const float* __restrict__ ea, const int* __restrict__ srcp,
    const int* __restrict__ dstp, const int* __restrict__ offs,
    int* __restrict__ runc, int* __restrict__ ssrc,
    unsigned short* __restrict__ ea_s) {
    for (int e = blockIdx.x * blockDim.x + threadIdx.x; e < N_EDGES;
         e += gridDim.x * blockDim.x) {
        const int d = dstp[e];
        const int p = offs[d] + atomicAdd(&runc[d], 1);
        ssrc[p] = srcp[e];
        const float* er = ea + (size_t)e * 32;
        unsigned short* op = ea_s + (size_t)p * 32;
#pragma unroll
        for (int sgm = 0; sgm < 4; ++sgm) {
            const float4 v0 = *(const float4*)(er + sgm * 8);
            const float4 v1 = *(const float4*)(er + sgm * 8 + 4);
            ushort8 u;
            u[0] = f2bf(v0.x); u[1] = f2bf(v0.y); u[2] = f2bf(v0.z); u[3] = f2bf(v0.w);
            u[4] = f2bf(v1.x); u[5] = f2bf(v1.y); u[6] = f2bf(v1.z); u[7] = f2bf(v1.w);
            *(ushort8*)(op + sgm * 8) = u;
        }
    }
}

// Fallback: perm + ssrc only (R3 path)
__global__ __launch_bounds__(256) void csr_scatter(
    const int* __restrict__ srcp, const int* __restrict__ dstp,
    const int* __restrict__ offs, int* __restrict__ runc,
    int* __restrict__ perm, int* __restrict__ ssrc) {
    for (int e = blockIdx.x * blockDim.x + threadIdx.x; e < N_EDGES;
         e += gridDim.x * blockDim.x) {
        const int d = dstp[e];
        const int p = offs[d] + atomicAdd(&runc[d], 1);
        perm[p] = e;
        ssrc[p] = srcp[e];
    }
}

// ---------------------------------------------------------------------------
// Gather (primary): one wave per node, ea_s pre-sorted bf16 -> A-frag is a
// single coalesced 16B load per lane. msg = relu(x[src]+ea@W+b), reduce in
// regs + shfl_xor across quads, one 256B store. No atomics.
// ---------------------------------------------------------------------------
__global__ __launch_bounds__(256) void gine_gather_bf(
    const float* __restrict__ xin,          // [N,64]
    const unsigned short* __restrict__ eas, // [E,32] bf16, dst-sorted
    const int*   __restrict__ ssrc,         // [E] src in sorted order
    const int*   __restrict__ offs,         // [N+1]
    const float* __restrict__ linW,         // [32,64]
    const float* __restrict__ linB,         // [64]
    float*       __restrict__ agg)          // [N,64]
{
    const int lane = threadIdx.x & 63;
    const int gwave  = (blockIdx.x * blockDim.x + threadIdx.x) >> 6;
    const int nwaves = (gridDim.x * blockDim.x) >> 6;
    const int row  = lane & 15;
    const int quad = lane >> 4;

    bf16x8 wf[4];
#pragma unroll
    for (int t = 0; t < 4; ++t) {
        ushort8 us;
#pragma unroll
        for (int j = 0; j < 8; ++j)
            us[j] = f2bf(linW[(quad * 8 + j) * 64 + t * 16 + row]);
        wf[t] = __builtin_bit_cast(bf16x8, us);
    }
    float bias[4];
#pragma unroll
    for (int t = 0; t < 4; ++t) bias[t] = linB[t * 16 + row];

    for (int n = gwave; n < N_NODES; n += nwaves) {
        const int start = offs[n];
        const int end   = offs[n + 1];

        float s0 = 0.f, s1 = 0.f, s2 = 0.f, s3 = 0.f;

        for (int base = start; base < end; base += 16) {
            ushort8 ua = {0, 0, 0, 0, 0, 0, 0, 0};
            const int eidx = base + row;
            if (eidx < end)
                ua = *(const ushort8*)(eas + (size_t)eidx * 32 + quad * 8);
            const bf16x8 af = __builtin_bit_cast(bf16x8, ua);

            f32x4 acc[4];
#pragma unroll
            for (int t = 0; t < 4; ++t)
                acc[t] = __builtin_amdgcn_mfma_f32_16x16x32_bf16(
                    af, wf[t], (f32x4){0.f, 0.f, 0.f, 0.f}, 0, 0, 0);

#pragma unroll
            for (int r = 0; r < 4; ++r) {
                const int ei = base + quad * 4 + r;
                if (ei < end) {
                    const int s = ssrc[ei];
                    const float* xrow = xin + (size_t)s * 64;
                    s0 += fmaxf(xrow[ 0 + row] + bias[0] + acc[0][r], 0.f);
                    s1 += fmaxf(xrow[16 + row] + bias[1] + acc[1][r], 0.f);
                    s2 += fmaxf(xrow[32 + row] + bias[2] + acc[2][r], 0.f);
                    s3 += fmaxf(xrow[48 + row] + bias[3] + acc[3][r], 0.f);
                }
            }
        }

        s0 += __shfl_xor(s0, 16); s0 += __shfl_xor(s0, 32);
        s1 += __shfl_xor(s1, 16); s1 += __shfl_xor(s1, 32);
        s2 += __shfl_xor(s2, 16); s2 += __shfl_xor(s2, 32);
        s3 += __shfl_xor(s3, 16); s3 += __shfl_xor(s3, 32);

        const float v = (quad == 0) ? s0 : (quad == 1) ? s1
                       : (quad == 2) ? s2 : s3;
        agg[(size_t)n * 64 + lane] = v;
    }
}

// Fallback gather (fp32 ea via perm) — R3-proven
__global__ __launch_bounds__(256) void gine_gather_fp32(
    const float* __restrict__ xin, const float* __restrict__ ea,
    const int* __restrict__ perm, const int* __restrict__ ssrc,
    const int* __restrict__ offs, const float* __restrict__ linW,
    const float* __restrict__ linB, float* __restrict__ agg)
{
    const int lane = threadIdx.x & 63;
    const int gwave  = (blockIdx.x * blockDim.x + threadIdx.x) >> 6;
    const int nwaves = (gridDim.x * blockDim.x) >> 6;
    const int row  = lane & 15;
    const int quad = lane >> 4;

    bf16x8 wf[4];
#pragma unroll
    for (int t = 0; t < 4; ++t) {
        ushort8 us;
#pragma unroll
        for (int j = 0; j < 8; ++j)
            us[j] = f2bf(linW[(quad * 8 + j) * 64 + t * 16 + row]);
        wf[t] = __builtin_bit_cast(bf16x8, us);
    }
    float bias[4];
#pragma unroll
    for (int t = 0; t < 4; ++t) bias[t] = linB[t * 16 + row];

    for (int n = gwave; n < N_NODES; n += nwaves) {
        const int start = offs[n];
        const int end   = offs[n + 1];
        float s0 = 0.f, s1 = 0.f, s2 = 0.f, s3 = 0.f;

        for (int base = start; base < end; base += 16) {
            ushort8 ua = {0, 0, 0, 0, 0, 0, 0, 0};
            const int eidx = base + row;
            if (eidx < end) {
                const int e = perm[eidx];
                const float* ap = ea + (size_t)e * 32 + quad * 8;
                const float4 a0 = *(const float4*)ap;
                const float4 a1 = *(const float4*)(ap + 4);
                ua[0] = f2bf(a0.x); ua[1] = f2bf(a0.y);
                ua[2] = f2bf(a0.z); ua[3] = f2bf(a0.w);
                ua[4] = f2bf(a1.x); ua[5] = f2bf(a1.y);
                ua[6] = f2bf(a1.z); ua[7] = f2bf(a1.w);
            }
            const bf16x8 af = __builtin_bit_cast(bf16x8, ua);

            f32x4 acc[4];
#pragma unroll
            for (int t = 0; t < 4; ++t)
                acc[t] = __builtin_amdgcn_mfma_f32_16x16x32_bf16(
                    af, wf[t], (f32x4){0.f, 0.f, 0.f, 0.f}, 0, 0, 0);

#pragma unroll
            for (int r = 0; r < 4; ++r) {
                const int ei = base + quad * 4 + r;
                if (ei < end) {
                    const int s = ssrc[ei];
                    const float* xrow = xin + (size_t)s * 64;
                    s0 += fmaxf(xrow[ 0 + row] + bias[0] + acc[0][r], 0.f);
                    s1 += fmaxf(xrow[16 + row] + bias[1] + acc[1][r], 0.f);
                    s2 += fmaxf(xrow[32 + row] + bias[2] + acc[2][r], 0.f);
                    s3 += fmaxf(xrow[48 + row] + bias[3] + acc[3][r], 0.f);
                }
            }
        }
        s0 += __shfl_xor(s0, 16); s0 += __shfl_xor(s0, 32);
        s1 += __shfl_xor(s1, 16); s1 += __shfl_xor(s1, 32);
        s2 += __shfl_xor(s2, 16); s2 += __shfl_xor(s2, 32);
        s3 += __shfl_xor(s3, 16); s3 += __shfl_xor(s3, 32);
        const float v = (quad == 0) ? s0 : (quad == 1) ? s1
                       : (quad == 2) ? s2 : s3;
        agg[(size_t)n * 64 + lane] = v;
    }
}

// ---------------------------------------------------------------------------
// Node MLP via MFMA, D[ch][node] orientation: A = W^T (preloaded frags),
// B = h^T (natural contiguous row load). One wave = 16 nodes.
// Inter-layer transpose via per-wave LDS (16 x 68 fp32), no barriers.
// ---------------------------------------------------------------------------
#define LSTRIDE 68

__global__ __launch_bounds__(256) void gine_node_mfma(
    const float* __restrict__ xin, const float* __restrict__ agg,
    const float* __restrict__ w1, const float* __restrict__ b1,
    const float* __restrict__ w2, const float* __restrict__ b2,
    float* __restrict__ hout)
{
    __shared__ float lds[4][16 * LSTRIDE];
    const int lane = threadIdx.x & 63;
    const int c = lane & 15, q = lane >> 4;
    float* L = lds[threadIdx.x >> 6];

    const int gwave  = (blockIdx.x * blockDim.x + threadIdx.x) >> 6;
    const int nwaves = (gridDim.x * blockDim.x) >> 6;

    bf16x8 a1[4][2], a2[4][2];
#pragma unroll
    for (int mt = 0; mt < 4; ++mt)
#pragma unroll
        for (int ks = 0; ks < 2; ++ks) {
            ushort8 u1, u2;
#pragma unroll
            for (int j = 0; j < 8; ++j) {
                const int k = ks * 32 + q * 8 + j;
                u1[j] = f2bf(w1[k * 64 + mt * 16 + c]);
                u2[j] = f2bf(w2[k * 64 + mt * 16 + c]);
            }
            a1[mt][ks] = __builtin_bit_cast(bf16x8, u1);
            a2[mt][ks] = __builtin_bit_cast(bf16x8, u2);
        }
    f32x4 b1v[4], b2v[4];
#pragma unroll
    for (int mt = 0; mt < 4; ++mt) {
        b1v[mt] = *(const f32x4*)(b1 + mt * 16 + q * 4);
        b2v[mt] = *(const f32x4*)(b2 + mt * 16 + q * 4);
    }

    const int ntiles = N_NODES / 16;   // 3125 exact
    for (int tile = gwave; tile < ntiles; tile += nwaves) {
        const int n0 = tile * 16;
        const float* xr = xin + (size_t)(n0 + c) * 64;
        const float* ar = agg + (size_t)(n0 + c) * 64;

        bf16x8 hb[2];
#pragma unroll
        for (int ks = 0; ks < 2; ++ks) {
            const int o = ks * 32 + q * 8;
            const float4 xa = *(const float4*)(xr + o);
            const float4 xb = *(const float4*)(xr + o + 4);
            const float4 aa = *(const float4*)(ar + o);
            const float4 ab = *(const float4*)(ar + o + 4);
            ushort8 u;
            u[0] = f2bf(xa.x + aa.x); u[1] = f2bf(xa.y + aa.y);
            u[2] = f2bf(xa.z + aa.z); u[3] = f2bf(xa.w + aa.w);
            u[4] = f2bf(xb.x + ab.x); u[5] = f2bf(xb.y + ab.y);
            u[6] = f2bf(xb.z + ab.z); u[7] = f2bf(xb.w + ab.w);
            hb[ks] = __builtin_bit_cast(bf16x8, u);
        }

        f32x4 acc[4];
#pragma unroll
        for (int mt = 0; mt < 4; ++mt) {
            acc[mt] = __builtin_amdgcn_mfma_f32_16x16x32_bf16(
                a1[mt][0], hb[0], (f32x4){0.f, 0.f, 0.f, 0.f}, 0, 0, 0);
            acc[mt] = __builtin_amdgcn_mfma_f32_16x16x32_bf16(
                a1[mt][1], hb[1], acc[mt], 0, 0, 0);
        }

        // relu+bias -> LDS [node][ch]
#pragma unroll
        for (int mt = 0; mt < 4; ++mt) {
            f32x4 t;
#pragma unroll
            for (int r = 0; r < 4; ++r) t[r] = fmaxf(acc[mt][r] + b1v[mt][r], 0.f);
            *(f32x4*)(L + c * LSTRIDE + mt * 16 + q * 4) = t;
        }
        asm volatile("s_waitcnt lgkmcnt(0)" ::: "memory");

        bf16x8 tb[2];
#pragma unroll
        for (int ks = 0; ks < 2; ++ks) {
            const f32x4 lo = *(const f32x4*)(L + c * LSTRIDE + ks * 32 + q * 8);
            const f32x4 hi = *(const f32x4*)(L + c * LSTRIDE + ks * 32 + q * 8 + 4);
            ushort8 u;
            u[0] = f2bf(lo[0]); u[1] = f2bf(lo[1]); u[2] = f2bf(lo[2]); u[3] = f2bf(lo[3]);
            u[4] = f2bf(hi[0]); u[5] = f2bf(hi[1]); u[6] = f2bf(hi[2]); u[7] = f2bf(hi[3]);
            tb[ks] = __builtin_bit_cast(bf16x8, u);
        }
        asm volatile("s_waitcnt lgkmcnt(0)" ::: "memory");

#pragma unroll
        for (int mt = 0; mt < 4; ++mt) {
            acc[mt] = __builtin_amdgcn_mfma_f32_16x16x32_bf16(
                a2[mt][0], tb[0], (f32x4){0.f, 0.f, 0.f, 0.f}, 0, 0, 0);
            acc[mt] = __builtin_amdgcn_mfma_f32_16x16x32_bf16(
                a2[mt][1], tb[1], acc[mt], 0, 0, 0);
        }

        float* hr = hout + (size_t)(n0 + c) * 64;
#pragma unroll
        for (int mt = 0; mt < 4; ++mt) {
            f32x4 u;
#pragma unroll
            for (int r = 0; r < 4; ++r) u[r] = fmaxf(acc[mt][r] + b2v[mt][r], 0.f);
            *(f32x4*)(hr + mt * 16 + q * 4) = u;
        }
    }
}

__global__ __launch_bounds__(256) void gine_node_head_mfma(
    const float* __restrict__ xin, const float* __restrict__ agg,
    const float* __restrict__ w1, const float* __restrict__ b1,
    const float* __restrict__ w2, const float* __restrict__ b2,
    const float* __restrict__ hw, const float* __restrict__ hbp,
    float* __restrict__ outp)
{
    __shared__ float lds[4][16 * LSTRIDE];
    const int lane = threadIdx.x & 63;
    const int c = lane & 15, q = lane >> 4;
    float* L = lds[threadIdx.x >> 6];

    const int gwave  = (blockIdx.x * blockDim.x + threadIdx.x) >> 6;
    const int nwaves = (gridDim.x * blockDim.x) >> 6;

    bf16x8 a1[4][2], a2[4][2], a3[2][2];
#pragma unroll
    for (int mt = 0; mt < 4; ++mt)
#pragma unroll
        for (int ks = 0; ks < 2; ++ks) {
            ushort8 u1, u2;
#pragma unroll
            for (int j = 0; j < 8; ++j) {
                const int k = ks * 32 + q * 8 + j;
                u1[j] = f2bf(w1[k * 64 + mt * 16 + c]);
                u2[j] = f2bf(w2[k * 64 + mt * 16 + c]);
            }
            a1[mt][ks] = __builtin_bit_cast(bf16x8, u1);
            a2[mt][ks] = __builtin_bit_cast(bf16x8, u2);
        }
#pragma unroll
    for (int mt = 0; mt < 2; ++mt)
#pragma unroll
        for (int ks = 0; ks < 2; ++ks) {
            ushort8 u3;
#pragma unroll
            for (int j = 0; j < 8; ++j) {
                const int k = ks * 32 + q * 8 + j;
                u3[j] = f2bf(hw[k * 32 + mt * 16 + c]);
            }
            a3[mt][ks] = __builtin_bit_cast(bf16x8, u3);
        }
    f32x4 b1v[4], b2v[4], hbv[2];
#pragma unroll
    for (int mt = 0; mt < 4; ++mt) {
        b1v[mt] = *(const f32x4*)(b1 + mt * 16 + q * 4);
        b2v[mt] = *(const f32x4*)(b2 + mt * 16 + q * 4);
    }
#pragma unroll
    for (int mt = 0; mt < 2; ++mt)
        hbv[mt] = *(const f32x4*)(hbp + mt * 16 + q * 4);

    const int ntiles = N_NODES / 16;
    for (int tile = gwave; tile < ntiles; tile += nwaves) {
        const int n0 = tile * 16;
        const float* xr = xin + (size_t)(n0 + c) * 64;
        const float* ar = agg + (size_t)(n0 + c) * 64;

        bf16x8 hb[2];
#pragma unroll
        for (int ks = 0; ks < 2; ++ks) {
            const int o = ks * 32 + q * 8;
            const float4 xa = *(const float4*)(xr + o);
            const float4 xb = *(const float4*)(xr + o + 4);
            const float4 aa = *(const float4*)(ar + o);
            const float4 ab = *(const float4*)(ar + o + 4);
            ushort8 u;
            u[0] = f2bf(xa.x + aa.x); u[1] = f2bf(xa.y + aa.y);
            u[2] = f2bf(xa.z + aa.z); u[3] = f2bf(xa.w + aa.w);
            u[4] = f2bf(xb.x + ab.x); u[5] = f2bf(xb.y + ab.y);
            u[6] = f2bf(xb.z + ab.z); u[7] = f2bf(xb.w + ab.w);
            hb[ks] = __builtin_bit_cast(bf16x8, u);
        }

        f32x4 acc[4];
#pragma unroll
        for (int mt = 0; mt < 4; ++mt) {
            acc[mt] = __builtin_amdgcn_mfma_f32_16x16x32_bf16(
                a1[mt][0], hb[0], (f32x4){0.f, 0.f, 0.f, 0.f}, 0, 0, 0);
            acc[mt] = __builtin_amdgcn_mfma_f32_16x16x32_bf16(
                a1[mt][1], hb[1], acc[mt], 0, 0, 0);
        }

#pragma unroll
        for (int mt = 0; mt < 4; ++mt) {
            f32x4 t;
#pragma unroll
            for (int r = 0; r < 4; ++r) t[r] = fmaxf(acc[mt][r] + b1v[mt][r], 0.f);
            *(f32x4*)(L + c * LSTRIDE + mt * 16 + q * 4) = t;
        }
        asm volatile("s_waitcnt lgkmcnt(0)" ::: "memory");

        bf16x8 tb[2];
#pragma unroll
        for (int ks = 0; ks < 2; ++ks) {
            const f32x4 lo = *(const f32x4*)(L + c * LSTRIDE + ks * 32 + q * 8);
            const f32x4 hi = *(const f32x4*)(L + c * LSTRIDE + ks * 32 + q * 8 + 4);
            ushort8 u;
            u[0] = f2bf(lo[0]); u[1] = f2bf(lo[1]); u[2] = f2bf(lo[2]); u[3] = f2bf(lo[3]);
            u[4] = f2bf(hi[0]); u[5] = f2bf(hi[1]); u[6] = f2bf(hi[2]); u[7] = f2bf(hi[3]);
            tb[ks] = __builtin_bit_cast(bf16x8, u);
        }
        asm volatile("s_waitcnt lgkmcnt(0)" ::: "memory");

#pragma unroll
        for (int mt = 0; mt < 4; ++mt) {
            acc[mt] = __builtin_amdgcn_mfma_f32_16x16x32_bf16(
                a2[mt][0], tb[0], (f32x4){0.f, 0.f, 0.f, 0.f}, 0, 0, 0);
            acc[mt] = __builtin_amdgcn_mfma_f32_16x16x32_bf16(
                a2[mt][1], tb[1], acc[mt], 0, 0, 0);
        }

        // u = relu(.. + b2) -> LDS again for head B-frag
#pragma unroll
        for (int mt = 0; mt < 4; ++mt) {
            f32x4 t;
#pragma unroll
            for (int r = 0; r < 4; ++r) t[r] = fmaxf(acc[mt][r] + b2v[mt][r], 0.f);
            *(f32x4*)(L + c * LSTRIDE + mt * 16 + q * 4) = t;
        }
        asm volatile("s_waitcnt lgkmcnt(0)" ::: "memory");

        bf16x8 ub[2];
#pragma unroll
        for (int ks = 0; ks < 2; ++ks) {
            const f32x4 lo = *(const f32x4*)(L + c * LSTRIDE + ks * 32 + q * 8);
            const f32x4 hi = *(const f32x4*)(L + c * LSTRIDE + ks * 32 + q * 8 + 4);
            ushort8 u;
            u[0] = f2bf(lo[0]); u[1] = f2bf(lo[1]); u[2] = f2bf(lo[2]); u[3] = f2bf(lo[3]);
            u[4] = f2bf(hi[0]); u[5] = f2bf(hi[1]); u[6] = f2bf(hi[2]); u[7] = f2bf(hi[3]);
            ub[ks] = __builtin_bit_cast(bf16x8, u);
        }
        asm volatile("s_waitcnt lgkmcnt(0)" ::: "memory");

        f32x4 acc3[2];
#pragma unroll
        for (int mt = 0; mt < 2; ++mt) {
            acc3[mt] = __builtin_amdgcn_mfma_f32_16x16x32_bf16(
                a3[mt][0], ub[0], (f32x4){0.f, 0.f, 0.f, 0.f}, 0, 0, 0);
            acc3[mt] = __builtin_amdgcn_mfma_f32_16x16x32_bf16(
                a3[mt][1], ub[1], acc3[mt], 0, 0, 0);
        }

        float* outr = outp + (size_t)(n0 + c) * 32;
#pragma unroll
        for (int mt = 0; mt < 2; ++mt) {
            f32x4 u;
#pragma unroll
            for (int r = 0; r < 4; ++r) u[r] = acc3[mt][r] + hbv[mt][r];
            *(f32x4*)(outr + mt * 16 + q * 4) = u;
        }
    }
}

extern "C" void kernel_launch(void* const* d_in, const int* in_sizes, int n_in,
                              void* d_out, int out_size, void* d_ws, size_t ws_size,
                              hipStream_t stream) {
    const float* x     = (const float*)d_in[0];
    const float* ea    = (const float*)d_in[1];
    const int*   ei    = (const int*)  d_in[2];
    const float* c1lw  = (const float*)d_in[3];
    const float* c1lb  = (const float*)d_in[4];
    const float* c1w1  = (const float*)d_in[5];
    const float* c1b1  = (const float*)d_in[6];
    const float* c1w2  = (const float*)d_in[7];
    const float* c1b2  = (const float*)d_in[8];
    const float* c2lw  = (const float*)d_in[9];
    const float* c2lb  = (const float*)d_in[10];
    const float* c2w1  = (const float*)d_in[11];
    const float* c2b1  = (const float*)d_in[12];
    const float* c2w2  = (const float*)d_in[13];
    const float* c2b2  = (const float*)d_in[14];
    const float* hw    = (const float*)d_in[15];
    const float* hb    = (const float*)d_in[16];

    const int* srcp = ei;
    const int* dstp = ei + N_EDGES;

    float* agg  = (float*)d_ws;                       // [N,64]
    float* h1   = agg + (size_t)N_NODES * 64;         // [N,64]
    int*   cnt  = (int*)(h1 + (size_t)N_NODES * 64);  // [N]
    int*   offs = cnt + N_NODES;                      // [N+1]
    int*   runc = offs + (N_NODES + 1);               // [N]
    int*   ssrc = runc + N_NODES;                     // [E]
    // tail region: either ea_s (bf16 [E,32]) or perm ([E])
    size_t tail_off = ((size_t)((char*)(ssrc + N_EDGES) - (char*)d_ws) + 63) & ~(size_t)63;
    unsigned short* ea_s = (unsigned short*)((char*)d_ws + tail_off);
    int*            perm = (int*)((char*)d_ws + tail_off);
    const bool primary = ws_size >= tail_off + (size_t)N_EDGES * 32 * sizeof(unsigned short) + 64;

    float* outp = (float*)d_out;

    hipMemsetAsync(cnt,  0, N_NODES * sizeof(int), stream);
    hipMemsetAsync(runc, 0, N_NODES * sizeof(int), stream);
    hipLaunchKernelGGL(csr_hist, dim3(1024), dim3(256), 0, stream, dstp, cnt);
    hipLaunchKernelGGL(csr_scan, dim3(1),    dim3(1024), 0, stream, cnt, offs);

    if (primary) {
        hipLaunchKernelGGL(csr_scatter_ea, dim3(3125), dim3(256), 0, stream,
                           ea, srcp, dstp, offs, runc, ssrc, ea_s);
        hipLaunchKernelGGL(gine_gather_bf, dim3(2048), dim3(256), 0, stream,
                           x, ea_s, ssrc, offs, c1lw, c1lb, agg);
        hipLaunchKernelGGL(gine_node_mfma, dim3(800), dim3(256), 0, stream,
                           x, agg, c1w1, c1b1, c1w2, c1b2, h1);
        hipLaunchKernelGGL(gine_gather_bf, dim3(2048), dim3(256), 0, stream,
                           h1, ea_s, ssrc, offs, c2lw, c2lb, agg);
        hipLaunchKernelGGL(gine_node_head_mfma, dim3(800), dim3(256), 0, stream,
                           h1, agg, c2w1, c2b1, c2w2, c2b2, hw, hb, outp);
    } else {
        hipLaunchKernelGGL(csr_scatter, dim3(1024), dim3(256), 0, stream,
                           srcp, dstp, offs, runc, perm, ssrc);
        hipLaunchKernelGGL(gine_gather_fp32, dim3(2048), dim3(256), 0, stream,
                           x, ea, perm, ssrc, offs, c1lw, c1lb, agg);
        hipLaunchKernelGGL(gine_node_mfma, dim3(800), dim3(256), 0, stream,
                           x, agg, c1w1, c1b1, c1w2, c1b2, h1);
        hipLaunchKernelGGL(gine_gather_fp32, dim3(2048), dim3(256), 0, stream,
                           h1, ea, perm, ssrc, offs, c2lw, c2lb, agg);
        hipLaunchKernelGGL(gine_node_head_mfma, dim3(800), dim3(256), 0, stream,
                           h1, agg, c2w1, c2b1, c2w2, c2b2, hw, hb, outp);
    }
}

// Round 5
// 450.159 us; speedup vs baseline: 1.3125x; 1.1219x over previous
//
#include <hip/hip_runtime.h>

#define N_NODES 50000
#define N_EDGES 800000

typedef __bf16 bf16x8 __attribute__((ext_vector_type(8)));
typedef unsigned short ushort8 __attribute__((ext_vector_type(8)));
typedef float f32x4 __attribute__((ext_vector_type(4)));

__device__ __forceinline__ unsigned short f2bf(float f) {
    unsigned u = __builtin_bit_cast(unsigned, f);
    u += 0x7fffu + ((u >> 16) & 1u);
    return (unsigned short)(u >> 16);
}

// ---------------------------------------------------------------------------
// CSR build: hist -> 3-phase parallel scan -> perm scatter -> gather-permute
// ---------------------------------------------------------------------------
__global__ __launch_bounds__(256) void csr_hist(const int* __restrict__ dstp,
                                                int* __restrict__ cnt) {
    for (int e = blockIdx.x * blockDim.x + threadIdx.x; e < N_EDGES;
         e += gridDim.x * blockDim.x)
        atomicAdd(&cnt[dstp[e]], 1);
}

// phase 1: per-block sums (256 blocks x 256 threads, <=1 elem/thread)
__global__ __launch_bounds__(256) void scan_p1(const int* __restrict__ cnt,
                                               int* __restrict__ bsum) {
    __shared__ int sm[256];
    const int t = threadIdx.x;
    const int idx = blockIdx.x * 256 + t;
    sm[t] = (idx < N_NODES) ? cnt[idx] : 0;
    __syncthreads();
    for (int off = 128; off > 0; off >>= 1) {
        if (t < off) sm[t] += sm[t + off];
        __syncthreads();
    }
    if (t == 0) bsum[blockIdx.x] = sm[0];
}

// phase 2: exclusive scan of 256 block sums (1 block)
__global__ __launch_bounds__(256) void scan_p2(const int* __restrict__ bsum,
                                               int* __restrict__ bpre,
                                               int* __restrict__ offs) {
    __shared__ int sm[256];
    const int t = threadIdx.x;
    int v = bsum[t];
    sm[t] = v;
    __syncthreads();
    for (int off = 1; off < 256; off <<= 1) {
        int u = (t >= off) ? sm[t - off] : 0;
        __syncthreads();
        sm[t] += u;
        __syncthreads();
    }
    bpre[t] = sm[t] - v;               // exclusive
    if (t == 255) offs[N_NODES] = sm[255];
}

// phase 3: block-local exclusive scan + block prefix
__global__ __launch_bounds__(256) void scan_p3(const int* __restrict__ cnt,
                                               const int* __restrict__ bpre,
                                               int* __restrict__ offs) {
    __shared__ int sm[256];
    const int t = threadIdx.x;
    const int idx = blockIdx.x * 256 + t;
    const int v = (idx < N_NODES) ? cnt[idx] : 0;
    sm[t] = v;
    __syncthreads();
    for (int off = 1; off < 256; off <<= 1) {
        int u = (t >= off) ? sm[t - off] : 0;
        __syncthreads();
        sm[t] += u;
        __syncthreads();
    }
    if (idx < N_NODES) offs[idx] = bpre[blockIdx.x] + sm[t] - v;
}

// scatter perm only (4B scattered writes, L2-absorbed)
__global__ __launch_bounds__(256) void csr_scatter_perm(
    const int* __restrict__ dstp, const int* __restrict__ offs,
    int* __restrict__ runc, int* __restrict__ perm) {
    for (int e = blockIdx.x * blockDim.x + threadIdx.x; e < N_EDGES;
         e += gridDim.x * blockDim.x) {
        const int d = dstp[e];
        const int p = offs[d] + atomicAdd(&runc[d], 1);
        perm[p] = e;
    }
}

// gather-style permute: coalesced perm read, whole-line random ea read,
// coalesced ea_s/ssrc writes (no write amplification)
__global__ __launch_bounds__(256) void csr_permute_ea(
    const float* __restrict__ ea, const int* __restrict__ srcp,
    const int* __restrict__ perm, int* __restrict__ ssrc,
    unsigned short* __restrict__ ea_s) {
    for (int p = blockIdx.x * blockDim.x + threadIdx.x; p < N_EDGES;
         p += gridDim.x * blockDim.x) {
        const int e = perm[p];
        ssrc[p] = srcp[e];
        const float* er = ea + (size_t)e * 32;
        unsigned short* op = ea_s + (size_t)p * 32;
#pragma unroll
        for (int sgm = 0; sgm < 4; ++sgm) {
            const float4 v0 = *(const float4*)(er + sgm * 8);
            const float4 v1 = *(const float4*)(er + sgm * 8 + 4);
            ushort8 u;
            u[0] = f2bf(v0.x); u[1] = f2bf(v0.y); u[2] = f2bf(v0.z); u[3] = f2bf(v0.w);
            u[4] = f2bf(v1.x); u[5] = f2bf(v1.y); u[6] = f2bf(v1.z); u[7] = f2bf(v1.w);
            *(ushort8*)(op + sgm * 8) = u;
        }
    }
}

// fallback scatter (perm + ssrc to tail) — R3 path
__global__ __launch_bounds__(256) void csr_scatter(
    const int* __restrict__ srcp, const int* __restrict__ dstp,
    const int* __restrict__ offs, int* __restrict__ runc,
    int* __restrict__ perm, int* __restrict__ ssrc) {
    for (int e = blockIdx.x * blockDim.x + threadIdx.x; e < N_EDGES;
         e += gridDim.x * blockDim.x) {
        const int d = dstp[e];
        const int p = offs[d] + atomicAdd(&runc[d], 1);
        perm[p] = e;
        ssrc[p] = srcp[e];
    }
}

// ---------------------------------------------------------------------------
// Gather (primary): one wave per node, ea_s pre-sorted bf16; MFMA; no atomics.
// ---------------------------------------------------------------------------
__global__ __launch_bounds__(256) void gine_gather_bf(
    const float* __restrict__ xin,
    const unsigned short* __restrict__ eas,
    const int*   __restrict__ ssrc,
    const int*   __restrict__ offs,
    const float* __restrict__ linW,
    const float* __restrict__ linB,
    float*       __restrict__ agg)
{
    const int lane = threadIdx.x & 63;
    const int gwave  = (blockIdx.x * blockDim.x + threadIdx.x) >> 6;
    const int nwaves = (gridDim.x * blockDim.x) >> 6;
    const int row  = lane & 15;
    const int quad = lane >> 4;

    bf16x8 wf[4];
#pragma unroll
    for (int t = 0; t < 4; ++t) {
        ushort8 us;
#pragma unroll
        for (int j = 0; j < 8; ++j)
            us[j] = f2bf(linW[(quad * 8 + j) * 64 + t * 16 + row]);
        wf[t] = __builtin_bit_cast(bf16x8, us);
    }
    float bias[4];
#pragma unroll
    for (int t = 0; t < 4; ++t) bias[t] = linB[t * 16 + row];

    for (int n = gwave; n < N_NODES; n += nwaves) {
        const int start = offs[n];
        const int end   = offs[n + 1];

        float s0 = 0.f, s1 = 0.f, s2 = 0.f, s3 = 0.f;

        for (int base = start; base < end; base += 16) {
            ushort8 ua = {0, 0, 0, 0, 0, 0, 0, 0};
            const int eidx = base + row;
            if (eidx < end)
                ua = *(const ushort8*)(eas + (size_t)eidx * 32 + quad * 8);
            const bf16x8 af = __builtin_bit_cast(bf16x8, ua);

            f32x4 acc[4];
#pragma unroll
            for (int t = 0; t < 4; ++t)
                acc[t] = __builtin_amdgcn_mfma_f32_16x16x32_bf16(
                    af, wf[t], (f32x4){0.f, 0.f, 0.f, 0.f}, 0, 0, 0);

#pragma unroll
            for (int r = 0; r < 4; ++r) {
                const int ei = base + quad * 4 + r;
                if (ei < end) {
                    const int s = ssrc[ei];
                    const float* xrow = xin + (size_t)s * 64;
                    s0 += fmaxf(xrow[ 0 + row] + bias[0] + acc[0][r], 0.f);
                    s1 += fmaxf(xrow[16 + row] + bias[1] + acc[1][r], 0.f);
                    s2 += fmaxf(xrow[32 + row] + bias[2] + acc[2][r], 0.f);
                    s3 += fmaxf(xrow[48 + row] + bias[3] + acc[3][r], 0.f);
                }
            }
        }

        s0 += __shfl_xor(s0, 16); s0 += __shfl_xor(s0, 32);
        s1 += __shfl_xor(s1, 16); s1 += __shfl_xor(s1, 32);
        s2 += __shfl_xor(s2, 16); s2 += __shfl_xor(s2, 32);
        s3 += __shfl_xor(s3, 16); s3 += __shfl_xor(s3, 32);

        const float v = (quad == 0) ? s0 : (quad == 1) ? s1
                       : (quad == 2) ? s2 : s3;
        agg[(size_t)n * 64 + lane] = v;
    }
}

// fallback gather (fp32 ea via perm)
__global__ __launch_bounds__(256) void gine_gather_fp32(
    const float* __restrict__ xin, const float* __restrict__ ea,
    const int* __restrict__ perm, const int* __restrict__ ssrc,
    const int* __restrict__ offs, const float* __restrict__ linW,
    const float* __restrict__ linB, float* __restrict__ agg)
{
    const int lane = threadIdx.x & 63;
    const int gwave  = (blockIdx.x * blockDim.x + threadIdx.x) >> 6;
    const int nwaves = (gridDim.x * blockDim.x) >> 6;
    const int row  = lane & 15;
    const int quad = lane >> 4;

    bf16x8 wf[4];
#pragma unroll
    for (int t = 0; t < 4; ++t) {
        ushort8 us;
#pragma unroll
        for (int j = 0; j < 8; ++j)
            us[j] = f2bf(linW[(quad * 8 + j) * 64 + t * 16 + row]);
        wf[t] = __builtin_bit_cast(bf16x8, us);
    }
    float bias[4];
#pragma unroll
    for (int t = 0; t < 4; ++t) bias[t] = linB[t * 16 + row];

    for (int n = gwave; n < N_NODES; n += nwaves) {
        const int start = offs[n];
        const int end   = offs[n + 1];
        float s0 = 0.f, s1 = 0.f, s2 = 0.f, s3 = 0.f;

        for (int base = start; base < end; base += 16) {
            ushort8 ua = {0, 0, 0, 0, 0, 0, 0, 0};
            const int eidx = base + row;
            if (eidx < end) {
                const int e = perm[eidx];
                const float* ap = ea + (size_t)e * 32 + quad * 8;
                const float4 a0 = *(const float4*)ap;
                const float4 a1 = *(const float4*)(ap + 4);
                ua[0] = f2bf(a0.x); ua[1] = f2bf(a0.y);
                ua[2] = f2bf(a0.z); ua[3] = f2bf(a0.w);
                ua[4] = f2bf(a1.x); ua[5] = f2bf(a1.y);
                ua[6] = f2bf(a1.z); ua[7] = f2bf(a1.w);
            }
            const bf16x8 af = __builtin_bit_cast(bf16x8, ua);

            f32x4 acc[4];
#pragma unroll
            for (int t = 0; t < 4; ++t)
                acc[t] = __builtin_amdgcn_mfma_f32_16x16x32_bf16(
                    af, wf[t], (f32x4){0.f, 0.f, 0.f, 0.f}, 0, 0, 0);

#pragma unroll
            for (int r = 0; r < 4; ++r) {
                const int ei = base + quad * 4 + r;
                if (ei < end) {
                    const int s = ssrc[ei];
                    const float* xrow = xin + (size_t)s * 64;
                    s0 += fmaxf(xrow[ 0 + row] + bias[0] + acc[0][r], 0.f);
                    s1 += fmaxf(xrow[16 + row] + bias[1] + acc[1][r], 0.f);
                    s2 += fmaxf(xrow[32 + row] + bias[2] + acc[2][r], 0.f);
                    s3 += fmaxf(xrow[48 + row] + bias[3] + acc[3][r], 0.f);
                }
            }
        }
        s0 += __shfl_xor(s0, 16); s0 += __shfl_xor(s0, 32);
        s1 += __shfl_xor(s1, 16); s1 += __shfl_xor(s1, 32);
        s2 += __shfl_xor(s2, 16); s2 += __shfl_xor(s2, 32);
        s3 += __shfl_xor(s3, 16); s3 += __shfl_xor(s3, 32);
        const float v = (quad == 0) ? s0 : (quad == 1) ? s1
                       : (quad == 2) ? s2 : s3;
        agg[(size_t)n * 64 + lane] = v;
    }
}

// ---------------------------------------------------------------------------
// Node MLP via MFMA (one wave = 16 nodes), per-wave LDS transpose.
// ---------------------------------------------------------------------------
#define LSTRIDE 68

__global__ __launch_bounds__(256) void gine_node_mfma(
    const float* __restrict__ xin, const float* __restrict__ agg,
    const float* __restrict__ w1, const float* __restrict__ b1,
    const float* __restrict__ w2, const float* __restrict__ b2,
    float* __restrict__ hout)
{
    __shared__ float lds[4][16 * LSTRIDE];
    const int lane = threadIdx.x & 63;
    const int c = lane & 15, q = lane >> 4;
    float* L = lds[threadIdx.x >> 6];

    const int gwave  = (blockIdx.x * blockDim.x + threadIdx.x) >> 6;
    const int nwaves = (gridDim.x * blockDim.x) >> 6;

    bf16x8 a1[4][2], a2[4][2];
#pragma unroll
    for (int mt = 0; mt < 4; ++mt)
#pragma unroll
        for (int ks = 0; ks < 2; ++ks) {
            ushort8 u1, u2;
#pragma unroll
            for (int j = 0; j < 8; ++j) {
                const int k = ks * 32 + q * 8 + j;
                u1[j] = f2bf(w1[k * 64 + mt * 16 + c]);
                u2[j] = f2bf(w2[k * 64 + mt * 16 + c]);
            }
            a1[mt][ks] = __builtin_bit_cast(bf16x8, u1);
            a2[mt][ks] = __builtin_bit_cast(bf16x8, u2);
        }
    f32x4 b1v[4], b2v[4];
#pragma unroll
    for (int mt = 0; mt < 4; ++mt) {
        b1v[mt] = *(const f32x4*)(b1 + mt * 16 + q * 4);
        b2v[mt] = *(const f32x4*)(b2 + mt * 16 + q * 4);
    }

    const int ntiles = N_NODES / 16;   // 3125 exact
    for (int tile = gwave; tile < ntiles; tile += nwaves) {
        const int n0 = tile * 16;
        const float* xr = xin + (size_t)(n0 + c) * 64;
        const float* ar = agg + (size_t)(n0 + c) * 64;

        bf16x8 hb[2];
#pragma unroll
        for (int ks = 0; ks < 2; ++ks) {
            const int o = ks * 32 + q * 8;
            const float4 xa = *(const float4*)(xr + o);
            const float4 xb = *(const float4*)(xr + o + 4);
            const float4 aa = *(const float4*)(ar + o);
            const float4 ab = *(const float4*)(ar + o + 4);
            ushort8 u;
            u[0] = f2bf(xa.x + aa.x); u[1] = f2bf(xa.y + aa.y);
            u[2] = f2bf(xa.z + aa.z); u[3] = f2bf(xa.w + aa.w);
            u[4] = f2bf(xb.x + ab.x); u[5] = f2bf(xb.y + ab.y);
            u[6] = f2bf(xb.z + ab.z); u[7] = f2bf(xb.w + ab.w);
            hb[ks] = __builtin_bit_cast(bf16x8, u);
        }

        f32x4 acc[4];
#pragma unroll
        for (int mt = 0; mt < 4; ++mt) {
            acc[mt] = __builtin_amdgcn_mfma_f32_16x16x32_bf16(
                a1[mt][0], hb[0], (f32x4){0.f, 0.f, 0.f, 0.f}, 0, 0, 0);
            acc[mt] = __builtin_amdgcn_mfma_f32_16x16x32_bf16(
                a1[mt][1], hb[1], acc[mt], 0, 0, 0);
        }

#pragma unroll
        for (int mt = 0; mt < 4; ++mt) {
            f32x4 t;
#pragma unroll
            for (int r = 0; r < 4; ++r) t[r] = fmaxf(acc[mt][r] + b1v[mt][r], 0.f);
            *(f32x4*)(L + c * LSTRIDE + mt * 16 + q * 4) = t;
        }
        asm volatile("s_waitcnt lgkmcnt(0)" ::: "memory");

        bf16x8 tb[2];
#pragma unroll
        for (int ks = 0; ks < 2; ++ks) {
            const f32x4 lo = *(const f32x4*)(L + c * LSTRIDE + ks * 32 + q * 8);
            const f32x4 hi = *(const f32x4*)(L + c * LSTRIDE + ks * 32 + q * 8 + 4);
            ushort8 u;
            u[0] = f2bf(lo[0]); u[1] = f2bf(lo[1]); u[2] = f2bf(lo[2]); u[3] = f2bf(lo[3]);
            u[4] = f2bf(hi[0]); u[5] = f2bf(hi[1]); u[6] = f2bf(hi[2]); u[7] = f2bf(hi[3]);
            tb[ks] = __builtin_bit_cast(bf16x8, u);
        }
        asm volatile("s_waitcnt lgkmcnt(0)" ::: "memory");

#pragma unroll
        for (int mt = 0; mt < 4; ++mt) {
            acc[mt] = __builtin_amdgcn_mfma_f32_16x16x32_bf16(
                a2[mt][0], tb[0], (f32x4){0.f, 0.f, 0.f, 0.f}, 0, 0, 0);
            acc[mt] = __builtin_amdgcn_mfma_f32_16x16x32_bf16(
                a2[mt][1], tb[1], acc[mt], 0, 0, 0);
        }

        float* hr = hout + (size_t)(n0 + c) * 64;
#pragma unroll
        for (int mt = 0; mt < 4; ++mt) {
            f32x4 u;
#pragma unroll
            for (int r = 0; r < 4; ++r) u[r] = fmaxf(acc[mt][r] + b2v[mt][r], 0.f);
            *(f32x4*)(hr + mt * 16 + q * 4) = u;
        }
    }
}

__global__ __launch_bounds__(256) void gine_node_head_mfma(
    const float* __restrict__ xin, const float* __restrict__ agg,
    const float* __restrict__ w1, const float* __restrict__ b1,
    const float* __restrict__ w2, const float* __restrict__ b2,
    const float* __restrict__ hw, const float* __restrict__ hbp,
    float* __restrict__ outp)
{
    __shared__ float lds[4][16 * LSTRIDE];
    const int lane = threadIdx.x & 63;
    const int c = lane & 15, q = lane >> 4;
    float* L = lds[threadIdx.x >> 6];

    const int gwave  = (blockIdx.x * blockDim.x + threadIdx.x) >> 6;
    const int nwaves = (gridDim.x * blockDim.x) >> 6;

    bf16x8 a1[4][2], a2[4][2], a3[2][2];
#pragma unroll
    for (int mt = 0; mt < 4; ++mt)
#pragma unroll
        for (int ks = 0; ks < 2; ++ks) {
            ushort8 u1, u2;
#pragma unroll
            for (int j = 0; j < 8; ++j) {
                const int k = ks * 32 + q * 8 + j;
                u1[j] = f2bf(w1[k * 64 + mt * 16 + c]);
                u2[j] = f2bf(w2[k * 64 + mt * 16 + c]);
            }
            a1[mt][ks] = __builtin_bit_cast(bf16x8, u1);
            a2[mt][ks] = __builtin_bit_cast(bf16x8, u2);
        }
#pragma unroll
    for (int mt = 0; mt < 2; ++mt)
#pragma unroll
        for (int ks = 0; ks < 2; ++ks) {
            ushort8 u3;
#pragma unroll
            for (int j = 0; j < 8; ++j) {
                const int k = ks * 32 + q * 8 + j;
                u3[j] = f2bf(hw[k * 32 + mt * 16 + c]);
            }
            a3[mt][ks] = __builtin_bit_cast(bf16x8, u3);
        }
    f32x4 b1v[4], b2v[4], hbv[2];
#pragma unroll
    for (int mt = 0; mt < 4; ++mt) {
        b1v[mt] = *(const f32x4*)(b1 + mt * 16 + q * 4);
        b2v[mt] = *(const f32x4*)(b2 + mt * 16 + q * 4);
    }
#pragma unroll
    for (int mt = 0; mt < 2; ++mt)
        hbv[mt] = *(const f32x4*)(hbp + mt * 16 + q * 4);

    const int ntiles = N_NODES / 16;
    for (int tile = gwave; tile < ntiles; tile += nwaves) {
        const int n0 = tile * 16;
        const float* xr = xin + (size_t)(n0 + c) * 64;
        const float* ar = agg + (size_t)(n0 + c) * 64;

        bf16x8 hb[2];
#pragma unroll
        for (int ks = 0; ks < 2; ++ks) {
            const int o = ks * 32 + q * 8;
            const float4 xa = *(const float4*)(xr + o);
            const float4 xb = *(const float4*)(xr + o + 4);
            const float4 aa = *(const float4*)(ar + o);
            const float4 ab = *(const float4*)(ar + o + 4);
            ushort8 u;
            u[0] = f2bf(xa.x + aa.x); u[1] = f2bf(xa.y + aa.y);
            u[2] = f2bf(xa.z + aa.z); u[3] = f2bf(xa.w + aa.w);
            u[4] = f2bf(xb.x + ab.x); u[5] = f2bf(xb.y + ab.y);
            u[6] = f2bf(xb.z + ab.z); u[7] = f2bf(xb.w + ab.w);
            hb[ks] = __builtin_bit_cast(bf16x8, u);
        }

        f32x4 acc[4];
#pragma unroll
        for (int mt = 0; mt < 4; ++mt) {
            acc[mt] = __builtin_amdgcn_mfma_f32_16x16x32_bf16(
                a1[mt][0], hb[0], (f32x4){0.f, 0.f, 0.f, 0.f}, 0, 0, 0);
            acc[mt] = __builtin_amdgcn_mfma_f32_16x16x32_bf16(
                a1[mt][1], hb[1], acc[mt], 0, 0, 0);
        }

#pragma unroll
        for (int mt = 0; mt < 4; ++mt) {
            f32x4 t;
#pragma unroll
            for (int r = 0; r < 4; ++r) t[r] = fmaxf(acc[mt][r] + b1v[mt][r], 0.f);
            *(f32x4*)(L + c * LSTRIDE + mt * 16 + q * 4) = t;
        }
        asm volatile("s_waitcnt lgkmcnt(0)" ::: "memory");

        bf16x8 tb[2];
#pragma unroll
        for (int ks = 0; ks < 2; ++ks) {
            const f32x4 lo = *(const f32x4*)(L + c * LSTRIDE + ks * 32 + q * 8);
            const f32x4 hi = *(const f32x4*)(L + c * LSTRIDE + ks * 32 + q * 8 + 4);
            ushort8 u;
            u[0] = f2bf(lo[0]); u[1] = f2bf(lo[1]); u[2] = f2bf(lo[2]); u[3] = f2bf(lo[3]);
            u[4] = f2bf(hi[0]); u[5] = f2bf(hi[1]); u[6] = f2bf(hi[2]); u[7] = f2bf(hi[3]);
            tb[ks] = __builtin_bit_cast(bf16x8, u);
        }
        asm volatile("s_waitcnt lgkmcnt(0)" ::: "memory");

#pragma unroll
        for (int mt = 0; mt < 4; ++mt) {
            acc[mt] = __builtin_amdgcn_mfma_f32_16x16x32_bf16(
                a2[mt][0], tb[0], (f32x4){0.f, 0.f, 0.f, 0.f}, 0, 0, 0);
            acc[mt] = __builtin_amdgcn_mfma_f32_16x16x32_bf16(
                a2[mt][1], tb[1], acc[mt], 0, 0, 0);
        }

#pragma unroll
        for (int mt = 0; mt < 4; ++mt) {
            f32x4 t;
#pragma unroll
            for (int r = 0; r < 4; ++r) t[r] = fmaxf(acc[mt][r] + b2v[mt][r], 0.f);
            *(f32x4*)(L + c * LSTRIDE + mt * 16 + q * 4) = t;
        }
        asm volatile("s_waitcnt lgkmcnt(0)" ::: "memory");

        bf16x8 ub[2];
#pragma unroll
        for (int ks = 0; ks < 2; ++ks) {
            const f32x4 lo = *(const f32x4*)(L + c * LSTRIDE + ks * 32 + q * 8);
            const f32x4 hi = *(const f32x4*)(L + c * LSTRIDE + ks * 32 + q * 8 + 4);
            ushort8 u;
            u[0] = f2bf(lo[0]); u[1] = f2bf(lo[1]); u[2] = f2bf(lo[2]); u[3] = f2bf(lo[3]);
            u[4] = f2bf(hi[0]); u[5] = f2bf(hi[1]); u[6] = f2bf(hi[2]); u[7] = f2bf(hi[3]);
            ub[ks] = __builtin_bit_cast(bf16x8, u);
        }
        asm volatile("s_waitcnt lgkmcnt(0)" ::: "memory");

        f32x4 acc3[2];
#pragma unroll
        for (int mt = 0; mt < 2; ++mt) {
            acc3[mt] = __builtin_amdgcn_mfma_f32_16x16x32_bf16(
                a3[mt][0], ub[0], (f32x4){0.f, 0.f, 0.f, 0.f}, 0, 0, 0);
            acc3[mt] = __builtin_amdgcn_mfma_f32_16x16x32_bf16(
                a3[mt][1], ub[1], acc3[mt], 0, 0, 0);
        }

        float* outr = outp + (size_t)(n0 + c) * 32;
#pragma unroll
        for (int mt = 0; mt < 2; ++mt) {
            f32x4 u;
#pragma unroll
            for (int r = 0; r < 4; ++r) u[r] = acc3[mt][r] + hbv[mt][r];
            *(f32x4*)(outr + mt * 16 + q * 4) = u;
        }
    }
}

extern "C" void kernel_launch(void* const* d_in, const int* in_sizes, int n_in,
                              void* d_out, int out_size, void* d_ws, size_t ws_size,
                              hipStream_t stream) {
    const float* x     = (const float*)d_in[0];
    const float* ea    = (const float*)d_in[1];
    const int*   ei    = (const int*)  d_in[2];
    const float* c1lw  = (const float*)d_in[3];
    const float* c1lb  = (const float*)d_in[4];
    const float* c1w1  = (const float*)d_in[5];
    const float* c1b1  = (const float*)d_in[6];
    const float* c1w2  = (const float*)d_in[7];
    const float* c1b2  = (const float*)d_in[8];
    const float* c2lw  = (const float*)d_in[9];
    const float* c2lb  = (const float*)d_in[10];
    const float* c2w1  = (const float*)d_in[11];
    const float* c2b1  = (const float*)d_in[12];
    const float* c2w2  = (const float*)d_in[13];
    const float* c2b2  = (const float*)d_in[14];
    const float* hw    = (const float*)d_in[15];
    const float* hb    = (const float*)d_in[16];

    const int* srcp = ei;
    const int* dstp = ei + N_EDGES;

    float* agg  = (float*)d_ws;                       // [N,64]
    float* h1   = agg + (size_t)N_NODES * 64;         // [N,64]
    int*   cnt  = (int*)(h1 + (size_t)N_NODES * 64);  // [N]
    int*   offs = cnt + N_NODES;                      // [N+1]
    int*   runc = offs + (N_NODES + 1);               // [N]
    int*   bsum = runc + N_NODES;                     // [256]
    int*   bpre = bsum + 256;                         // [256]
    int*   ssrc = bpre + 256;                         // [E]
    size_t tail_off = ((size_t)((char*)(ssrc + N_EDGES) - (char*)d_ws) + 63) & ~(size_t)63;
    unsigned short* ea_s = (unsigned short*)((char*)d_ws + tail_off);   // [E,32] bf16
    int*            perm_tail = (int*)((char*)d_ws + tail_off);         // fallback [E]
    const bool primary = ws_size >= tail_off + (size_t)N_EDGES * 32 * sizeof(unsigned short) + 64;

    // primary: perm aliases h1 (only needed before h1 is written)
    int* perm = primary ? (int*)h1 : perm_tail;

    float* outp = (float*)d_out;
    const int SCAN_G = (N_NODES + 255) / 256;   // 196 blocks

    hipMemsetAsync(cnt,  0, N_NODES * sizeof(int), stream);
    hipMemsetAsync(runc, 0, N_NODES * sizeof(int), stream);
    hipLaunchKernelGGL(csr_hist, dim3(1024), dim3(256), 0, stream, dstp, cnt);
    // 3-phase scan: p1 over 256 virtual blocks (pad with zeros past SCAN_G)
    hipMemsetAsync(bsum, 0, 256 * sizeof(int), stream);
    hipLaunchKernelGGL(scan_p1, dim3(SCAN_G), dim3(256), 0, stream, cnt, bsum);
    hipLaunchKernelGGL(scan_p2, dim3(1),      dim3(256), 0, stream, bsum, bpre, offs);
    hipLaunchKernelGGL(scan_p3, dim3(SCAN_G), dim3(256), 0, stream, cnt, bpre, offs);

    if (primary) {
        hipLaunchKernelGGL(csr_scatter_perm, dim3(1024), dim3(256), 0, stream,
                           dstp, offs, runc, perm);
        hipLaunchKernelGGL(csr_permute_ea, dim3(2048), dim3(256), 0, stream,
                           ea, srcp, perm, ssrc, ea_s);
        hipLaunchKernelGGL(gine_gather_bf, dim3(4096), dim3(256), 0, stream,
                           x, ea_s, ssrc, offs, c1lw, c1lb, agg);
        hipLaunchKernelGGL(gine_node_mfma, dim3(800), dim3(256), 0, stream,
                           x, agg, c1w1, c1b1, c1w2, c1b2, h1);
        hipLaunchKernelGGL(gine_gather_bf, dim3(4096), dim3(256), 0, stream,
                           h1, ea_s, ssrc, offs, c2lw, c2lb, agg);
        hipLaunchKernelGGL(gine_node_head_mfma, dim3(800), dim3(256), 0, stream,
                           h1, agg, c2w1, c2b1, c2w2, c2b2, hw, hb, outp);
    } else {
        hipLaunchKernelGGL(csr_scatter, dim3(1024), dim3(256), 0, stream,
                           srcp, dstp, offs, runc, perm, ssrc);
        hipLaunchKernelGGL(gine_gather_fp32, dim3(4096), dim3(256), 0, stream,
                           x, ea, perm, ssrc, offs, c1lw, c1lb, agg);
        hipLaunchKernelGGL(gine_node_mfma, dim3(800), dim3(256), 0, stream,
                           x, agg, c1w1, c1b1, c1w2, c1b2, h1);
        hipLaunchKernelGGL(gine_gather_fp32, dim3(4096), dim3(256), 0, stream,
                           h1, ea, perm, ssrc, offs, c2lw, c2lb, agg);
        hipLaunchKernelGGL(gine_node_head_mfma, dim3(800), dim3(256), 0, stream,
                           h1, agg, c2w1, c2b1, c2w2, c2b2, hw, hb, outp);
    }
}

// Round 6
// 391.120 us; speedup vs baseline: 1.5106x; 1.1509x over previous
//
#include <hip/hip_runtime.h>

#define N_NODES 50000
#define N_EDGES 800000

typedef __bf16 bf16x8 __attribute__((ext_vector_type(8)));
typedef unsigned short ushort8 __attribute__((ext_vector_type(8)));
typedef float f32x4 __attribute__((ext_vector_type(4)));

__device__ __forceinline__ unsigned short f2bf(float f) {
    unsigned u = __builtin_bit_cast(unsigned, f);
    u += 0x7fffu + ((u >> 16) & 1u);
    return (unsigned short)(u >> 16);
}

__device__ __forceinline__ f32x4 shfl_xor4(f32x4 v, int m) {
    f32x4 r;
    r[0] = __shfl_xor(v[0], m); r[1] = __shfl_xor(v[1], m);
    r[2] = __shfl_xor(v[2], m); r[3] = __shfl_xor(v[3], m);
    return r;
}
__device__ __forceinline__ f32x4 sel4(bool p, f32x4 a, f32x4 b) {
    f32x4 r;
    r[0] = p ? a[0] : b[0]; r[1] = p ? a[1] : b[1];
    r[2] = p ? a[2] : b[2]; r[3] = p ? a[3] : b[3];
    return r;
}

// agg channel permutation: channel ch stored at pos = ch[3:2]<<4 | ch[5:4]<<2 | ch[1:0]
// (bit-pair swap; 4-blocks stay contiguous). Writers: gather kernels. Readers: node kernels.

// ---------------------------------------------------------------------------
// CSR build: hist(+rank) -> 3-phase scan -> atomic-free perm scatter -> permute
// ---------------------------------------------------------------------------
__global__ __launch_bounds__(256) void csr_hist_rank(const int* __restrict__ dstp,
                                                     int* __restrict__ cnt,
                                                     int* __restrict__ rank) {
    for (int e = blockIdx.x * blockDim.x + threadIdx.x; e < N_EDGES;
         e += gridDim.x * blockDim.x)
        rank[e] = atomicAdd(&cnt[dstp[e]], 1);
}

__global__ __launch_bounds__(256) void scan_p1(const int* __restrict__ cnt,
                                               int* __restrict__ bsum) {
    __shared__ int sm[256];
    const int t = threadIdx.x;
    const int idx = blockIdx.x * 256 + t;
    sm[t] = (idx < N_NODES) ? cnt[idx] : 0;
    __syncthreads();
    for (int off = 128; off > 0; off >>= 1) {
        if (t < off) sm[t] += sm[t + off];
        __syncthreads();
    }
    if (t == 0) bsum[blockIdx.x] = sm[0];
}

__global__ __launch_bounds__(256) void scan_p2(const int* __restrict__ bsum,
                                               int* __restrict__ bpre,
                                               int* __restrict__ offs) {
    __shared__ int sm[256];
    const int t = threadIdx.x;
    int v = bsum[t];
    sm[t] = v;
    __syncthreads();
    for (int off = 1; off < 256; off <<= 1) {
        int u = (t >= off) ? sm[t - off] : 0;
        __syncthreads();
        sm[t] += u;
        __syncthreads();
    }
    bpre[t] = sm[t] - v;
    if (t == 255) offs[N_NODES] = sm[255];
}

__global__ __launch_bounds__(256) void scan_p3(const int* __restrict__ cnt,
                                               const int* __restrict__ bpre,
                                               int* __restrict__ offs) {
    __shared__ int sm[256];
    const int t = threadIdx.x;
    const int idx = blockIdx.x * 256 + t;
    const int v = (idx < N_NODES) ? cnt[idx] : 0;
    sm[t] = v;
    __syncthreads();
    for (int off = 1; off < 256; off <<= 1) {
        int u = (t >= off) ? sm[t - off] : 0;
        __syncthreads();
        sm[t] += u;
        __syncthreads();
    }
    if (idx < N_NODES) offs[idx] = bpre[blockIdx.x] + sm[t] - v;
}

// atomic-free scatter using precomputed rank
__global__ __launch_bounds__(256) void csr_scatter_perm_rank(
    const int* __restrict__ dstp, const int* __restrict__ rank,
    const int* __restrict__ offs, int* __restrict__ perm) {
    for (int e = blockIdx.x * blockDim.x + threadIdx.x; e < N_EDGES;
         e += gridDim.x * blockDim.x)
        perm[offs[dstp[e]] + rank[e]] = e;
}

// gather-style permute: coalesced writes, whole-line random ea reads
__global__ __launch_bounds__(256) void csr_permute_ea(
    const float* __restrict__ ea, const int* __restrict__ srcp,
    const int* __restrict__ perm, int* __restrict__ ssrc,
    unsigned short* __restrict__ ea_s) {
    for (int p = blockIdx.x * blockDim.x + threadIdx.x; p < N_EDGES;
         p += gridDim.x * blockDim.x) {
        const int e = perm[p];
        ssrc[p] = srcp[e];
        const float* er = ea + (size_t)e * 32;
        unsigned short* op = ea_s + (size_t)p * 32;
#pragma unroll
        for (int sgm = 0; sgm < 4; ++sgm) {
            const float4 v0 = *(const float4*)(er + sgm * 8);
            const float4 v1 = *(const float4*)(er + sgm * 8 + 4);
            ushort8 u;
            u[0] = f2bf(v0.x); u[1] = f2bf(v0.y); u[2] = f2bf(v0.z); u[3] = f2bf(v0.w);
            u[4] = f2bf(v1.x); u[5] = f2bf(v1.y); u[6] = f2bf(v1.z); u[7] = f2bf(v1.w);
            *(ushort8*)(op + sgm * 8) = u;
        }
    }
}

// fallback scatter (atomics, perm + ssrc)
__global__ __launch_bounds__(256) void csr_scatter(
    const int* __restrict__ srcp, const int* __restrict__ dstp,
    const int* __restrict__ offs, int* __restrict__ runc,
    int* __restrict__ perm, int* __restrict__ ssrc) {
    for (int e = blockIdx.x * blockDim.x + threadIdx.x; e < N_EDGES;
         e += gridDim.x * blockDim.x) {
        const int d = dstp[e];
        const int p = offs[d] + atomicAdd(&runc[d], 1);
        perm[p] = e;
        ssrc[p] = srcp[e];
    }
}

// ---------------------------------------------------------------------------
// Gather (primary), transposed orientation: D = W^T · ea^T  ->
//   D[m=channel][n=edge]; lane (q, c=lane&15) owns edge (base+c), channels
//   {mt*16 + q*4 + r}. x[src] gather = 4 coalesced float4 loads per lane.
//   Bias rides in the MFMA C operand. Per-node 15-shuffle merging butterfly,
//   store in bit-pair-swapped channel order (pos = ch[3:2]<<4|ch[5:4]<<2|ch[1:0]).
// ---------------------------------------------------------------------------
__global__ __launch_bounds__(256) void gine_gather_bf(
    const float* __restrict__ xin,
    const unsigned short* __restrict__ eas,
    const int*   __restrict__ ssrc,
    const int*   __restrict__ offs,
    const float* __restrict__ linW,
    const float* __restrict__ linB,
    float*       __restrict__ agg)
{
    const int lane = threadIdx.x & 63;
    const int gwave  = (blockIdx.x * blockDim.x + threadIdx.x) >> 6;
    const int nwaves = (gridDim.x * blockDim.x) >> 6;
    const int c = lane & 15;
    const int q = lane >> 4;

    // A-fragments (W^T chunks): wf[mt][j] = W[q*8+j][mt*16+c]
    bf16x8 wf[4];
#pragma unroll
    for (int mt = 0; mt < 4; ++mt) {
        ushort8 us;
#pragma unroll
        for (int j = 0; j < 8; ++j)
            us[j] = f2bf(linW[(q * 8 + j) * 64 + mt * 16 + c]);
        wf[mt] = __builtin_bit_cast(bf16x8, us);
    }
    // bias as MFMA C operand: C[m=q*4+r][n] = linB[mt*16+q*4+r]
    f32x4 biasv[4];
#pragma unroll
    for (int mt = 0; mt < 4; ++mt)
        biasv[mt] = *(const f32x4*)(linB + mt * 16 + q * 4);

    for (int n = gwave; n < N_NODES; n += nwaves) {
        const int start = offs[n];
        const int end   = offs[n + 1];

        f32x4 s0 = {0.f,0.f,0.f,0.f}, s1 = {0.f,0.f,0.f,0.f};
        f32x4 s2 = {0.f,0.f,0.f,0.f}, s3 = {0.f,0.f,0.f,0.f};

        for (int base = start; base < end; base += 16) {
            const int eidx = base + c;
            const bool valid = eidx < end;
            const int ecl = valid ? eidx : end - 1;

            // B-frag: ea row of this lane's edge (16B coalesced)
            const bf16x8 bf = __builtin_bit_cast(bf16x8,
                *(const ushort8*)(eas + (size_t)ecl * 32 + q * 8));

            f32x4 acc[4];
            acc[0] = __builtin_amdgcn_mfma_f32_16x16x32_bf16(wf[0], bf, biasv[0], 0, 0, 0);
            acc[1] = __builtin_amdgcn_mfma_f32_16x16x32_bf16(wf[1], bf, biasv[1], 0, 0, 0);
            acc[2] = __builtin_amdgcn_mfma_f32_16x16x32_bf16(wf[2], bf, biasv[2], 0, 0, 0);
            acc[3] = __builtin_amdgcn_mfma_f32_16x16x32_bf16(wf[3], bf, biasv[3], 0, 0, 0);

            const int s = ssrc[ecl];
            const float* xr = xin + (size_t)s * 64 + q * 4;
            f32x4 xv[4];
#pragma unroll
            for (int mt = 0; mt < 4; ++mt)
                xv[mt] = *(const f32x4*)(xr + mt * 16);

            const float NEG = -3.0e38f;
#pragma unroll
            for (int r = 0; r < 4; ++r) {
                s0[r] += fmaxf((valid ? xv[0][r] : NEG) + acc[0][r], 0.f);
                s1[r] += fmaxf((valid ? xv[1][r] : NEG) + acc[1][r], 0.f);
                s2[r] += fmaxf((valid ? xv[2][r] : NEG) + acc[2][r], 0.f);
                s3[r] += fmaxf((valid ? xv[3][r] : NEG) + acc[3][r], 0.f);
            }
        }

        // merging butterfly over c-bits: each step halves live registers
        // xor 8: select mt-pair by c3
        f32x4 t0 = sel4((c & 8) != 0, s2, s0) + shfl_xor4(sel4((c & 8) != 0, s0, s2), 8);
        f32x4 t1 = sel4((c & 8) != 0, s3, s1) + shfl_xor4(sel4((c & 8) != 0, s1, s3), 8);
        // xor 4: select mt within pair by c2  (mt = c>>2)
        f32x4 u = sel4((c & 4) != 0, t1, t0) + shfl_xor4(sel4((c & 4) != 0, t0, t1), 4);
        // xor 2: select r-pair by c1
        float v0 = ((c & 2) ? u[2] : u[0]) + __shfl_xor((c & 2) ? u[0] : u[2], 2);
        float v1 = ((c & 2) ? u[3] : u[1]) + __shfl_xor((c & 2) ? u[1] : u[3], 2);
        // xor 1: select r within pair by c0  (r = c&3)
        float w = ((c & 1) ? v1 : v0) + __shfl_xor((c & 1) ? v0 : v1, 1);

        // lane (q,c) holds channel (c>>2)*16 + q*4 + (c&3); store at position lane
        agg[(size_t)n * 64 + lane] = w;
    }
}

// fallback gather (fp32 ea via perm), old orientation, permuted agg store
__global__ __launch_bounds__(256) void gine_gather_fp32(
    const float* __restrict__ xin, const float* __restrict__ ea,
    const int* __restrict__ perm, const int* __restrict__ ssrc,
    const int* __restrict__ offs, const float* __restrict__ linW,
    const float* __restrict__ linB, float* __restrict__ agg)
{
    const int lane = threadIdx.x & 63;
    const int gwave  = (blockIdx.x * blockDim.x + threadIdx.x) >> 6;
    const int nwaves = (gridDim.x * blockDim.x) >> 6;
    const int row  = lane & 15;
    const int quad = lane >> 4;

    bf16x8 wf[4];
#pragma unroll
    for (int t = 0; t < 4; ++t) {
        ushort8 us;
#pragma unroll
        for (int j = 0; j < 8; ++j)
            us[j] = f2bf(linW[(quad * 8 + j) * 64 + t * 16 + row]);
        wf[t] = __builtin_bit_cast(bf16x8, us);
    }
    float bias[4];
#pragma unroll
    for (int t = 0; t < 4; ++t) bias[t] = linB[t * 16 + row];

    for (int n = gwave; n < N_NODES; n += nwaves) {
        const int start = offs[n];
        const int end   = offs[n + 1];
        float s0 = 0.f, s1 = 0.f, s2 = 0.f, s3 = 0.f;

        for (int base = start; base < end; base += 16) {
            ushort8 ua = {0, 0, 0, 0, 0, 0, 0, 0};
            const int eidx = base + row;
            if (eidx < end) {
                const int e = perm[eidx];
                const float* ap = ea + (size_t)e * 32 + quad * 8;
                const float4 a0 = *(const float4*)ap;
                const float4 a1 = *(const float4*)(ap + 4);
                ua[0] = f2bf(a0.x); ua[1] = f2bf(a0.y);
                ua[2] = f2bf(a0.z); ua[3] = f2bf(a0.w);
                ua[4] = f2bf(a1.x); ua[5] = f2bf(a1.y);
                ua[6] = f2bf(a1.z); ua[7] = f2bf(a1.w);
            }
            const bf16x8 af = __builtin_bit_cast(bf16x8, ua);

            f32x4 acc[4];
#pragma unroll
            for (int t = 0; t < 4; ++t)
                acc[t] = __builtin_amdgcn_mfma_f32_16x16x32_bf16(
                    af, wf[t], (f32x4){0.f, 0.f, 0.f, 0.f}, 0, 0, 0);

#pragma unroll
            for (int r = 0; r < 4; ++r) {
                const int ei = base + quad * 4 + r;
                if (ei < end) {
                    const int s = ssrc[ei];
                    const float* xrow = xin + (size_t)s * 64;
                    s0 += fmaxf(xrow[ 0 + row] + bias[0] + acc[0][r], 0.f);
                    s1 += fmaxf(xrow[16 + row] + bias[1] + acc[1][r], 0.f);
                    s2 += fmaxf(xrow[32 + row] + bias[2] + acc[2][r], 0.f);
                    s3 += fmaxf(xrow[48 + row] + bias[3] + acc[3][r], 0.f);
                }
            }
        }
        s0 += __shfl_xor(s0, 16); s0 += __shfl_xor(s0, 32);
        s1 += __shfl_xor(s1, 16); s1 += __shfl_xor(s1, 32);
        s2 += __shfl_xor(s2, 16); s2 += __shfl_xor(s2, 32);
        s3 += __shfl_xor(s3, 16); s3 += __shfl_xor(s3, 32);
        const float v = (quad == 0) ? s0 : (quad == 1) ? s1
                       : (quad == 2) ? s2 : s3;   // channel = lane
        const int pos = ((lane >> 2) & 3) * 16 + ((lane >> 4) & 3) * 4 + (lane & 3);
        agg[(size_t)n * 64 + pos] = v;
    }
}

// ---------------------------------------------------------------------------
// Node MLP via MFMA (one wave = 16 nodes), per-wave LDS transpose.
// agg is read with the bit-pair-swapped block permutation.
// ---------------------------------------------------------------------------
#define LSTRIDE 68

__global__ __launch_bounds__(256) void gine_node_mfma(
    const float* __restrict__ xin, const float* __restrict__ agg,
    const float* __restrict__ w1, const float* __restrict__ b1,
    const float* __restrict__ w2, const float* __restrict__ b2,
    float* __restrict__ hout)
{
    __shared__ float lds[4][16 * LSTRIDE];
    const int lane = threadIdx.x & 63;
    const int c = lane & 15, q = lane >> 4;
    float* L = lds[threadIdx.x >> 6];

    const int gwave  = (blockIdx.x * blockDim.x + threadIdx.x) >> 6;
    const int nwaves = (gridDim.x * blockDim.x) >> 6;

    bf16x8 a1[4][2], a2[4][2];
#pragma unroll
    for (int mt = 0; mt < 4; ++mt)
#pragma unroll
        for (int ks = 0; ks < 2; ++ks) {
            ushort8 u1, u2;
#pragma unroll
            for (int j = 0; j < 8; ++j) {
                const int k = ks * 32 + q * 8 + j;
                u1[j] = f2bf(w1[k * 64 + mt * 16 + c]);
                u2[j] = f2bf(w2[k * 64 + mt * 16 + c]);
            }
            a1[mt][ks] = __builtin_bit_cast(bf16x8, u1);
            a2[mt][ks] = __builtin_bit_cast(bf16x8, u2);
        }
    f32x4 b1v[4], b2v[4];
#pragma unroll
    for (int mt = 0; mt < 4; ++mt) {
        b1v[mt] = *(const f32x4*)(b1 + mt * 16 + q * 4);
        b2v[mt] = *(const f32x4*)(b2 + mt * 16 + q * 4);
    }

    const int ntiles = N_NODES / 16;
    for (int tile = gwave; tile < ntiles; tile += nwaves) {
        const int n0 = tile * 16;
        const float* xr = xin + (size_t)(n0 + c) * 64;
        const float* ar = agg + (size_t)(n0 + c) * 64;

        bf16x8 hb[2];
#pragma unroll
        for (int ks = 0; ks < 2; ++ks) {
            const int o = ks * 32 + q * 8;
            const int b0 = o >> 2, b1i = b0 + 1;
            const float4 xa = *(const float4*)(xr + o);
            const float4 xb = *(const float4*)(xr + o + 4);
            const float4 aa = *(const float4*)(ar + ((b0 & 3) * 16 + (b0 >> 2) * 4));
            const float4 ab = *(const float4*)(ar + ((b1i & 3) * 16 + (b1i >> 2) * 4));
            ushort8 u;
            u[0] = f2bf(xa.x + aa.x); u[1] = f2bf(xa.y + aa.y);
            u[2] = f2bf(xa.z + aa.z); u[3] = f2bf(xa.w + aa.w);
            u[4] = f2bf(xb.x + ab.x); u[5] = f2bf(xb.y + ab.y);
            u[6] = f2bf(xb.z + ab.z); u[7] = f2bf(xb.w + ab.w);
            hb[ks] = __builtin_bit_cast(bf16x8, u);
        }

        f32x4 acc[4];
#pragma unroll
        for (int mt = 0; mt < 4; ++mt) {
            acc[mt] = __builtin_amdgcn_mfma_f32_16x16x32_bf16(
                a1[mt][0], hb[0], (f32x4){0.f, 0.f, 0.f, 0.f}, 0, 0, 0);
            acc[mt] = __builtin_amdgcn_mfma_f32_16x16x32_bf16(
                a1[mt][1], hb[1], acc[mt], 0, 0, 0);
        }

#pragma unroll
        for (int mt = 0; mt < 4; ++mt) {
            f32x4 t;
#pragma unroll
            for (int r = 0; r < 4; ++r) t[r] = fmaxf(acc[mt][r] + b1v[mt][r], 0.f);
            *(f32x4*)(L + c * LSTRIDE + mt * 16 + q * 4) = t;
        }
        asm volatile("s_waitcnt lgkmcnt(0)" ::: "memory");

        bf16x8 tb[2];
#pragma unroll
        for (int ks = 0; ks < 2; ++ks) {
            const f32x4 lo = *(const f32x4*)(L + c * LSTRIDE + ks * 32 + q * 8);
            const f32x4 hi = *(const f32x4*)(L + c * LSTRIDE + ks * 32 + q * 8 + 4);
            ushort8 u;
            u[0] = f2bf(lo[0]); u[1] = f2bf(lo[1]); u[2] = f2bf(lo[2]); u[3] = f2bf(lo[3]);
            u[4] = f2bf(hi[0]); u[5] = f2bf(hi[1]); u[6] = f2bf(hi[2]); u[7] = f2bf(hi[3]);
            tb[ks] = __builtin_bit_cast(bf16x8, u);
        }
        asm volatile("s_waitcnt lgkmcnt(0)" ::: "memory");

#pragma unroll
        for (int mt = 0; mt < 4; ++mt) {
            acc[mt] = __builtin_amdgcn_mfma_f32_16x16x32_bf16(
                a2[mt][0], tb[0], (f32x4){0.f, 0.f, 0.f, 0.f}, 0, 0, 0);
            acc[mt] = __builtin_amdgcn_mfma_f32_16x16x32_bf16(
                a2[mt][1], tb[1], acc[mt], 0, 0, 0);
        }

        float* hr = hout + (size_t)(n0 + c) * 64;
#pragma unroll
        for (int mt = 0; mt < 4; ++mt) {
            f32x4 u;
#pragma unroll
            for (int r = 0; r < 4; ++r) u[r] = fmaxf(acc[mt][r] + b2v[mt][r], 0.f);
            *(f32x4*)(hr + mt * 16 + q * 4) = u;
        }
    }
}

__global__ __launch_bounds__(256) void gine_node_head_mfma(
    const float* __restrict__ xin, const float* __restrict__ agg,
    const float* __restrict__ w1, const float* __restrict__ b1,
    const float* __restrict__ w2, const float* __restrict__ b2,
    const float* __restrict__ hw, const float* __restrict__ hbp,
    float* __restrict__ outp)
{
    __shared__ float lds[4][16 * LSTRIDE];
    const int lane = threadIdx.x & 63;
    const int c = lane & 15, q = lane >> 4;
    float* L = lds[threadIdx.x >> 6];

    const int gwave  = (blockIdx.x * blockDim.x + threadIdx.x) >> 6;
    const int nwaves = (gridDim.x * blockDim.x) >> 6;

    bf16x8 a1[4][2], a2[4][2], a3[2][2];
#pragma unroll
    for (int mt = 0; mt < 4; ++mt)
#pragma unroll
        for (int ks = 0; ks < 2; ++ks) {
            ushort8 u1, u2;
#pragma unroll
            for (int j = 0; j < 8; ++j) {
                const int k = ks * 32 + q * 8 + j;
                u1[j] = f2bf(w1[k * 64 + mt * 16 + c]);
                u2[j] = f2bf(w2[k * 64 + mt * 16 + c]);
            }
            a1[mt][ks] = __builtin_bit_cast(bf16x8, u1);
            a2[mt][ks] = __builtin_bit_cast(bf16x8, u2);
        }
#pragma unroll
    for (int mt = 0; mt < 2; ++mt)
#pragma unroll
        for (int ks = 0; ks < 2; ++ks) {
            ushort8 u3;
#pragma unroll
            for (int j = 0; j < 8; ++j) {
                const int k = ks * 32 + q * 8 + j;
                u3[j] = f2bf(hw[k * 32 + mt * 16 + c]);
            }
            a3[mt][ks] = __builtin_bit_cast(bf16x8, u3);
        }
    f32x4 b1v[4], b2v[4], hbv[2];
#pragma unroll
    for (int mt = 0; mt < 4; ++mt) {
        b1v[mt] = *(const f32x4*)(b1 + mt * 16 + q * 4);
        b2v[mt] = *(const f32x4*)(b2 + mt * 16 + q * 4);
    }
#pragma unroll
    for (int mt = 0; mt < 2; ++mt)
        hbv[mt] = *(const f32x4*)(hbp + mt * 16 + q * 4);

    const int ntiles = N_NODES / 16;
    for (int tile = gwave; tile < ntiles; tile += nwaves) {
        const int n0 = tile * 16;
        const float* xr = xin + (size_t)(n0 + c) * 64;
        const float* ar = agg + (size_t)(n0 + c) * 64;

        bf16x8 hb[2];
#pragma unroll
        for (int ks = 0; ks < 2; ++ks) {
            const int o = ks * 32 + q * 8;
            const int b0 = o >> 2, b1i = b0 + 1;
            const float4 xa = *(const float4*)(xr + o);
            const float4 xb = *(const float4*)(xr + o + 4);
            const float4 aa = *(const float4*)(ar + ((b0 & 3) * 16 + (b0 >> 2) * 4));
            const float4 ab = *(const float4*)(ar + ((b1i & 3) * 16 + (b1i >> 2) * 4));
            ushort8 u;
            u[0] = f2bf(xa.x + aa.x); u[1] = f2bf(xa.y + aa.y);
            u[2] = f2bf(xa.z + aa.z); u[3] = f2bf(xa.w + aa.w);
            u[4] = f2bf(xb.x + ab.x); u[5] = f2bf(xb.y + ab.y);
            u[6] = f2bf(xb.z + ab.z); u[7] = f2bf(xb.w + ab.w);
            hb[ks] = __builtin_bit_cast(bf16x8, u);
        }

        f32x4 acc[4];
#pragma unroll
        for (int mt = 0; mt < 4; ++mt) {
            acc[mt] = __builtin_amdgcn_mfma_f32_16x16x32_bf16(
                a1[mt][0], hb[0], (f32x4){0.f, 0.f, 0.f, 0.f}, 0, 0, 0);
            acc[mt] = __builtin_amdgcn_mfma_f32_16x16x32_bf16(
                a1[mt][1], hb[1], acc[mt], 0, 0, 0);
        }

#pragma unroll
        for (int mt = 0; mt < 4; ++mt) {
            f32x4 t;
#pragma unroll
            for (int r = 0; r < 4; ++r) t[r] = fmaxf(acc[mt][r] + b1v[mt][r], 0.f);
            *(f32x4*)(L + c * LSTRIDE + mt * 16 + q * 4) = t;
        }
        asm volatile("s_waitcnt lgkmcnt(0)" ::: "memory");

        bf16x8 tb[2];
#pragma unroll
        for (int ks = 0; ks < 2; ++ks) {
            const f32x4 lo = *(const f32x4*)(L + c * LSTRIDE + ks * 32 + q * 8);
            const f32x4 hi = *(const f32x4*)(L + c * LSTRIDE + ks * 32 + q * 8 + 4);
            ushort8 u;
            u[0] = f2bf(lo[0]); u[1] = f2bf(lo[1]); u[2] = f2bf(lo[2]); u[3] = f2bf(lo[3]);
            u[4] = f2bf(hi[0]); u[5] = f2bf(hi[1]); u[6] = f2bf(hi[2]); u[7] = f2bf(hi[3]);
            tb[ks] = __builtin_bit_cast(bf16x8, u);
        }
        asm volatile("s_waitcnt lgkmcnt(0)" ::: "memory");

#pragma unroll
        for (int mt = 0; mt < 4; ++mt) {
            acc[mt] = __builtin_amdgcn_mfma_f32_16x16x32_bf16(
                a2[mt][0], tb[0], (f32x4){0.f, 0.f, 0.f, 0.f}, 0, 0, 0);
            acc[mt] = __builtin_amdgcn_mfma_f32_16x16x32_bf16(
                a2[mt][1], tb[1], acc[mt], 0, 0, 0);
        }

#pragma unroll
        for (int mt = 0; mt < 4; ++mt) {
            f32x4 t;
#pragma unroll
            for (int r = 0; r < 4; ++r) t[r] = fmaxf(acc[mt][r] + b2v[mt][r], 0.f);
            *(f32x4*)(L + c * LSTRIDE + mt * 16 + q * 4) = t;
        }
        asm volatile("s_waitcnt lgkmcnt(0)" ::: "memory");

        bf16x8 ub[2];
#pragma unroll
        for (int ks = 0; ks < 2; ++ks) {
            const f32x4 lo = *(const f32x4*)(L + c * LSTRIDE + ks * 32 + q * 8);
            const f32x4 hi = *(const f32x4*)(L + c * LSTRIDE + ks * 32 + q * 8 + 4);
            ushort8 u;
            u[0] = f2bf(lo[0]); u[1] = f2bf(lo[1]); u[2] = f2bf(lo[2]); u[3] = f2bf(lo[3]);
            u[4] = f2bf(hi[0]); u[5] = f2bf(hi[1]); u[6] = f2bf(hi[2]); u[7] = f2bf(hi[3]);
            ub[ks] = __builtin_bit_cast(bf16x8, u);
        }
        asm volatile("s_waitcnt lgkmcnt(0)" ::: "memory");

        f32x4 acc3[2];
#pragma unroll
        for (int mt = 0; mt < 2; ++mt) {
            acc3[mt] = __builtin_amdgcn_mfma_f32_16x16x32_bf16(
                a3[mt][0], ub[0], (f32x4){0.f, 0.f, 0.f, 0.f}, 0, 0, 0);
            acc3[mt] = __builtin_amdgcn_mfma_f32_16x16x32_bf16(
                a3[mt][1], ub[1], acc3[mt], 0, 0, 0);
        }

        float* outr = outp + (size_t)(n0 + c) * 32;
#pragma unroll
        for (int mt = 0; mt < 2; ++mt) {
            f32x4 u;
#pragma unroll
            for (int r = 0; r < 4; ++r) u[r] = acc3[mt][r] + hbv[mt][r];
            *(f32x4*)(outr + mt * 16 + q * 4) = u;
        }
    }
}

extern "C" void kernel_launch(void* const* d_in, const int* in_sizes, int n_in,
                              void* d_out, int out_size, void* d_ws, size_t ws_size,
                              hipStream_t stream) {
    const float* x     = (const float*)d_in[0];
    const float* ea    = (const float*)d_in[1];
    const int*   ei    = (const int*)  d_in[2];
    const float* c1lw  = (const float*)d_in[3];
    const float* c1lb  = (const float*)d_in[4];
    const float* c1w1  = (const float*)d_in[5];
    const float* c1b1  = (const float*)d_in[6];
    const float* c1w2  = (const float*)d_in[7];
    const float* c1b2  = (const float*)d_in[8];
    const float* c2lw  = (const float*)d_in[9];
    const float* c2lb  = (const float*)d_in[10];
    const float* c2w1  = (const float*)d_in[11];
    const float* c2b1  = (const float*)d_in[12];
    const float* c2w2  = (const float*)d_in[13];
    const float* c2b2  = (const float*)d_in[14];
    const float* hw    = (const float*)d_in[15];
    const float* hb    = (const float*)d_in[16];

    const int* srcp = ei;
    const int* dstp = ei + N_EDGES;

    float* agg  = (float*)d_ws;                       // [N,64]
    float* h1   = agg + (size_t)N_NODES * 64;         // [N,64]
    int*   cnt  = (int*)(h1 + (size_t)N_NODES * 64);  // [N]
    int*   offs = cnt + N_NODES;                      // [N+1]
    int*   runc = offs + (N_NODES + 1);               // [N] (fallback only)
    int*   bsum = runc + N_NODES;                     // [256]
    int*   bpre = bsum + 256;                         // [256]
    int*   ssrc = bpre + 256;                         // [E]
    int*   rank = ssrc + N_EDGES;                     // [E]
    size_t tail_off = ((size_t)((char*)(rank + N_EDGES) - (char*)d_ws) + 63) & ~(size_t)63;
    unsigned short* ea_s = (unsigned short*)((char*)d_ws + tail_off);   // [E,32] bf16
    int*            perm_tail = (int*)((char*)d_ws + tail_off);         // fallback [E]
    const bool primary = ws_size >= tail_off + (size_t)N_EDGES * 32 * sizeof(unsigned short) + 64;

    // primary: perm aliases h1 (only needed before h1 is written)
    int* perm = primary ? (int*)h1 : perm_tail;

    float* outp = (float*)d_out;
    const int SCAN_G = (N_NODES + 255) / 256;

    hipMemsetAsync(cnt, 0, N_NODES * sizeof(int), stream);
    hipLaunchKernelGGL(csr_hist_rank, dim3(2048), dim3(256), 0, stream, dstp, cnt, rank);
    hipMemsetAsync(bsum, 0, 256 * sizeof(int), stream);
    hipLaunchKernelGGL(scan_p1, dim3(SCAN_G), dim3(256), 0, stream, cnt, bsum);
    hipLaunchKernelGGL(scan_p2, dim3(1),      dim3(256), 0, stream, bsum, bpre, offs);
    hipLaunchKernelGGL(scan_p3, dim3(SCAN_G), dim3(256), 0, stream, cnt, bpre, offs);

    if (primary) {
        hipLaunchKernelGGL(csr_scatter_perm_rank, dim3(2048), dim3(256), 0, stream,
                           dstp, rank, offs, perm);
        hipLaunchKernelGGL(csr_permute_ea, dim3(4096), dim3(256), 0, stream,
                           ea, srcp, perm, ssrc, ea_s);
        hipLaunchKernelGGL(gine_gather_bf, dim3(4096), dim3(256), 0, stream,
                           x, ea_s, ssrc, offs, c1lw, c1lb, agg);
        hipLaunchKernelGGL(gine_node_mfma, dim3(800), dim3(256), 0, stream,
                           x, agg, c1w1, c1b1, c1w2, c1b2, h1);
        hipLaunchKernelGGL(gine_gather_bf, dim3(4096), dim3(256), 0, stream,
                           h1, ea_s, ssrc, offs, c2lw, c2lb, agg);
        hipLaunchKernelGGL(gine_node_head_mfma, dim3(800), dim3(256), 0, stream,
                           h1, agg, c2w1, c2b1, c2w2, c2b2, hw, hb, outp);
    } else {
        hipMemsetAsync(runc, 0, N_NODES * sizeof(int), stream);
        hipLaunchKernelGGL(csr_scatter, dim3(1024), dim3(256), 0, stream,
                           srcp, dstp, offs, runc, perm, ssrc);
        hipLaunchKernelGGL(gine_gather_fp32, dim3(4096), dim3(256), 0, stream,
                           x, ea, perm, ssrc, offs, c1lw, c1lb, agg);
        hipLaunchKernelGGL(gine_node_mfma, dim3(800), dim3(256), 0, stream,
                           x, agg, c1w1, c1b1, c1w2, c1b2, h1);
        hipLaunchKernelGGL(gine_gather_fp32, dim3(4096), dim3(256), 0, stream,
                           h1, ea, perm, ssrc, offs, c2lw, c2lb, agg);
        hipLaunchKernelGGL(gine_node_head_mfma, dim3(800), dim3(256), 0, stream,
                           h1, agg, c2w1, c2b1, c2w2, c2b2, hw, hb, outp);
    }
}

// Round 7
// 384.901 us; speedup vs baseline: 1.5350x; 1.0162x over previous
//
#include <hip/hip_runtime.h>

#define N_NODES 50000
#define N_EDGES 800000

typedef __bf16 bf16x8 __attribute__((ext_vector_type(8)));
typedef unsigned short ushort8 __attribute__((ext_vector_type(8)));
typedef float f32x4 __attribute__((ext_vector_type(4)));

__device__ __forceinline__ unsigned short f2bf(float f) {
    unsigned u = __builtin_bit_cast(unsigned, f);
    u += 0x7fffu + ((u >> 16) & 1u);
    return (unsigned short)(u >> 16);
}

__device__ __forceinline__ f32x4 shfl_xor4(f32x4 v, int m) {
    f32x4 r;
    r[0] = __shfl_xor(v[0], m); r[1] = __shfl_xor(v[1], m);
    r[2] = __shfl_xor(v[2], m); r[3] = __shfl_xor(v[3], m);
    return r;
}
__device__ __forceinline__ f32x4 sel4(bool p, f32x4 a, f32x4 b) {
    f32x4 r;
    r[0] = p ? a[0] : b[0]; r[1] = p ? a[1] : b[1];
    r[2] = p ? a[2] : b[2]; r[3] = p ? a[3] : b[3];
    return r;
}

// agg channel permutation: channel ch stored at pos = ch[3:2]<<4 | ch[5:4]<<2 | ch[1:0]
// (bit-pair swap; 4-blocks stay contiguous). Writers: gather kernels. Readers: node kernels.

// ---------------------------------------------------------------------------
// CSR build: hist(+rank) -> 3-phase scan -> atomic-free perm scatter -> permute
// ---------------------------------------------------------------------------
__global__ __launch_bounds__(256) void csr_hist_rank(const int* __restrict__ dstp,
                                                     int* __restrict__ cnt,
                                                     int* __restrict__ rank) {
    for (int e = blockIdx.x * blockDim.x + threadIdx.x; e < N_EDGES;
         e += gridDim.x * blockDim.x)
        rank[e] = atomicAdd(&cnt[dstp[e]], 1);
}

// launched with 256 blocks; blocks past N write 0 (replaces bsum memset)
__global__ __launch_bounds__(256) void scan_p1(const int* __restrict__ cnt,
                                               int* __restrict__ bsum) {
    __shared__ int sm[256];
    const int t = threadIdx.x;
    const int idx = blockIdx.x * 256 + t;
    sm[t] = (idx < N_NODES) ? cnt[idx] : 0;
    __syncthreads();
    for (int off = 128; off > 0; off >>= 1) {
        if (t < off) sm[t] += sm[t + off];
        __syncthreads();
    }
    if (t == 0) bsum[blockIdx.x] = sm[0];
}

__global__ __launch_bounds__(256) void scan_p2(const int* __restrict__ bsum,
                                               int* __restrict__ bpre,
                                               int* __restrict__ offs) {
    __shared__ int sm[256];
    const int t = threadIdx.x;
    int v = bsum[t];
    sm[t] = v;
    __syncthreads();
    for (int off = 1; off < 256; off <<= 1) {
        int u = (t >= off) ? sm[t - off] : 0;
        __syncthreads();
        sm[t] += u;
        __syncthreads();
    }
    bpre[t] = sm[t] - v;
    if (t == 255) offs[N_NODES] = sm[255];
}

__global__ __launch_bounds__(256) void scan_p3(const int* __restrict__ cnt,
                                               const int* __restrict__ bpre,
                                               int* __restrict__ offs) {
    __shared__ int sm[256];
    const int t = threadIdx.x;
    const int idx = blockIdx.x * 256 + t;
    const int v = (idx < N_NODES) ? cnt[idx] : 0;
    sm[t] = v;
    __syncthreads();
    for (int off = 1; off < 256; off <<= 1) {
        int u = (t >= off) ? sm[t - off] : 0;
        __syncthreads();
        sm[t] += u;
        __syncthreads();
    }
    if (idx < N_NODES) offs[idx] = bpre[blockIdx.x] + sm[t] - v;
}

// atomic-free scatter using precomputed rank
__global__ __launch_bounds__(256) void csr_scatter_perm_rank(
    const int* __restrict__ dstp, const int* __restrict__ rank,
    const int* __restrict__ offs, int* __restrict__ perm) {
    for (int e = blockIdx.x * blockDim.x + threadIdx.x; e < N_EDGES;
         e += gridDim.x * blockDim.x)
        perm[offs[dstp[e]] + rank[e]] = e;
}

// gather-style permute: coalesced writes, whole-line random ea reads
__global__ __launch_bounds__(256) void csr_permute_ea(
    const float* __restrict__ ea, const int* __restrict__ srcp,
    const int* __restrict__ perm, int* __restrict__ ssrc,
    unsigned short* __restrict__ ea_s) {
    for (int p = blockIdx.x * blockDim.x + threadIdx.x; p < N_EDGES;
         p += gridDim.x * blockDim.x) {
        const int e = perm[p];
        ssrc[p] = srcp[e];
        const float* er = ea + (size_t)e * 32;
        unsigned short* op = ea_s + (size_t)p * 32;
#pragma unroll
        for (int sgm = 0; sgm < 4; ++sgm) {
            const float4 v0 = *(const float4*)(er + sgm * 8);
            const float4 v1 = *(const float4*)(er + sgm * 8 + 4);
            ushort8 u;
            u[0] = f2bf(v0.x); u[1] = f2bf(v0.y); u[2] = f2bf(v0.z); u[3] = f2bf(v0.w);
            u[4] = f2bf(v1.x); u[5] = f2bf(v1.y); u[6] = f2bf(v1.z); u[7] = f2bf(v1.w);
            *(ushort8*)(op + sgm * 8) = u;
        }
    }
}

// fallback scatter (atomics, perm + ssrc)
__global__ __launch_bounds__(256) void csr_scatter(
    const int* __restrict__ srcp, const int* __restrict__ dstp,
    const int* __restrict__ offs, int* __restrict__ runc,
    int* __restrict__ perm, int* __restrict__ ssrc) {
    for (int e = blockIdx.x * blockDim.x + threadIdx.x; e < N_EDGES;
         e += gridDim.x * blockDim.x) {
        const int d = dstp[e];
        const int p = offs[d] + atomicAdd(&runc[d], 1);
        perm[p] = e;
        ssrc[p] = srcp[e];
    }
}

// ---------------------------------------------------------------------------
// Gather (primary), transposed orientation: D = W^T · ea^T  ->
//   D[m=channel][n=edge]; lane (q, c=lane&15) owns edge (base+c), channels
//   {mt*16 + q*4 + r}. x[src] gather = 4 coalesced float4 loads per lane.
//   Bias rides in the MFMA C operand.
//   Latency fix: whole-node src prefetch (1 coalesced load covers deg<=64),
//   per-tile src via __shfl — removes the per-tile ssrc->x dependent chain.
//   Per-node 15-shuffle merging butterfly; store in bit-pair-swapped order.
// ---------------------------------------------------------------------------
__global__ __launch_bounds__(256) void gine_gather_bf(
    const float* __restrict__ xin,
    const unsigned short* __restrict__ eas,
    const int*   __restrict__ ssrc,
    const int*   __restrict__ offs,
    const float* __restrict__ linW,
    const float* __restrict__ linB,
    float*       __restrict__ agg)
{
    const int lane = threadIdx.x & 63;
    const int gwave  = (blockIdx.x * blockDim.x + threadIdx.x) >> 6;
    const int nwaves = (gridDim.x * blockDim.x) >> 6;
    const int c = lane & 15;
    const int q = lane >> 4;

    // A-fragments (W^T chunks): wf[mt][j] = W[q*8+j][mt*16+c]
    bf16x8 wf[4];
#pragma unroll
    for (int mt = 0; mt < 4; ++mt) {
        ushort8 us;
#pragma unroll
        for (int j = 0; j < 8; ++j)
            us[j] = f2bf(linW[(q * 8 + j) * 64 + mt * 16 + c]);
        wf[mt] = __builtin_bit_cast(bf16x8, us);
    }
    // bias as MFMA C operand: C[m=q*4+r][n] = linB[mt*16+q*4+r]
    f32x4 biasv[4];
#pragma unroll
    for (int mt = 0; mt < 4; ++mt)
        biasv[mt] = *(const f32x4*)(linB + mt * 16 + q * 4);

    for (int n = gwave; n < N_NODES; n += nwaves) {
        const int start = offs[n];
        const int end   = offs[n + 1];

        // whole-node src prefetch: lane L holds ssrc[start+L] (clamped)
        const int pidx = (start + lane < end) ? (start + lane)
                                              : ((end > start) ? end - 1 : 0);
        const int sl = ssrc[pidx];

        f32x4 s0 = {0.f,0.f,0.f,0.f}, s1 = {0.f,0.f,0.f,0.f};
        f32x4 s2 = {0.f,0.f,0.f,0.f}, s3 = {0.f,0.f,0.f,0.f};

        int t = 0;
        for (int base = start; base < end; base += 16, ++t) {
            const int eidx = base + c;
            const bool valid = eidx < end;
            const int ecl = valid ? eidx : end - 1;

            // B-frag: ea row of this lane's edge (16B coalesced)
            const bf16x8 bf = __builtin_bit_cast(bf16x8,
                *(const ushort8*)(eas + (size_t)ecl * 32 + q * 8));

            // src: from prefetched register file (deg<=64), else rare load
            int s;
            if (t < 4) s = __shfl(sl, (t << 4) + c);
            else       s = ssrc[ecl];

            f32x4 acc[4];
            acc[0] = __builtin_amdgcn_mfma_f32_16x16x32_bf16(wf[0], bf, biasv[0], 0, 0, 0);
            acc[1] = __builtin_amdgcn_mfma_f32_16x16x32_bf16(wf[1], bf, biasv[1], 0, 0, 0);
            acc[2] = __builtin_amdgcn_mfma_f32_16x16x32_bf16(wf[2], bf, biasv[2], 0, 0, 0);
            acc[3] = __builtin_amdgcn_mfma_f32_16x16x32_bf16(wf[3], bf, biasv[3], 0, 0, 0);

            const float* xr = xin + (size_t)s * 64 + q * 4;
            f32x4 xv[4];
#pragma unroll
            for (int mt = 0; mt < 4; ++mt)
                xv[mt] = *(const f32x4*)(xr + mt * 16);

            const float NEG = -3.0e38f;
#pragma unroll
            for (int r = 0; r < 4; ++r) {
                s0[r] += fmaxf((valid ? xv[0][r] : NEG) + acc[0][r], 0.f);
                s1[r] += fmaxf((valid ? xv[1][r] : NEG) + acc[1][r], 0.f);
                s2[r] += fmaxf((valid ? xv[2][r] : NEG) + acc[2][r], 0.f);
                s3[r] += fmaxf((valid ? xv[3][r] : NEG) + acc[3][r], 0.f);
            }
        }

        // merging butterfly over c-bits
        f32x4 t0 = sel4((c & 8) != 0, s2, s0) + shfl_xor4(sel4((c & 8) != 0, s0, s2), 8);
        f32x4 t1 = sel4((c & 8) != 0, s3, s1) + shfl_xor4(sel4((c & 8) != 0, s1, s3), 8);
        f32x4 u = sel4((c & 4) != 0, t1, t0) + shfl_xor4(sel4((c & 4) != 0, t0, t1), 4);
        float v0 = ((c & 2) ? u[2] : u[0]) + __shfl_xor((c & 2) ? u[0] : u[2], 2);
        float v1 = ((c & 2) ? u[3] : u[1]) + __shfl_xor((c & 2) ? u[1] : u[3], 2);
        float w = ((c & 1) ? v1 : v0) + __shfl_xor((c & 1) ? v0 : v1, 1);

        // lane (q,c) holds channel (c>>2)*16 + q*4 + (c&3); store at position lane
        agg[(size_t)n * 64 + lane] = w;
    }
}

// fallback gather (fp32 ea via perm), old orientation, permuted agg store
__global__ __launch_bounds__(256) void gine_gather_fp32(
    const float* __restrict__ xin, const float* __restrict__ ea,
    const int* __restrict__ perm, const int* __restrict__ ssrc,
    const int* __restrict__ offs, const float* __restrict__ linW,
    const float* __restrict__ linB, float* __restrict__ agg)
{
    const int lane = threadIdx.x & 63;
    const int gwave  = (blockIdx.x * blockDim.x + threadIdx.x) >> 6;
    const int nwaves = (gridDim.x * blockDim.x) >> 6;
    const int row  = lane & 15;
    const int quad = lane >> 4;

    bf16x8 wf[4];
#pragma unroll
    for (int t = 0; t < 4; ++t) {
        ushort8 us;
#pragma unroll
        for (int j = 0; j < 8; ++j)
            us[j] = f2bf(linW[(quad * 8 + j) * 64 + t * 16 + row]);
        wf[t] = __builtin_bit_cast(bf16x8, us);
    }
    float bias[4];
#pragma unroll
    for (int t = 0; t < 4; ++t) bias[t] = linB[t * 16 + row];

    for (int n = gwave; n < N_NODES; n += nwaves) {
        const int start = offs[n];
        const int end   = offs[n + 1];
        float s0 = 0.f, s1 = 0.f, s2 = 0.f, s3 = 0.f;

        for (int base = start; base < end; base += 16) {
            ushort8 ua = {0, 0, 0, 0, 0, 0, 0, 0};
            const int eidx = base + row;
            if (eidx < end) {
                const int e = perm[eidx];
                const float* ap = ea + (size_t)e * 32 + quad * 8;
                const float4 a0 = *(const float4*)ap;
                const float4 a1 = *(const float4*)(ap + 4);
                ua[0] = f2bf(a0.x); ua[1] = f2bf(a0.y);
                ua[2] = f2bf(a0.z); ua[3] = f2bf(a0.w);
                ua[4] = f2bf(a1.x); ua[5] = f2bf(a1.y);
                ua[6] = f2bf(a1.z); ua[7] = f2bf(a1.w);
            }
            const bf16x8 af = __builtin_bit_cast(bf16x8, ua);

            f32x4 acc[4];
#pragma unroll
            for (int t = 0; t < 4; ++t)
                acc[t] = __builtin_amdgcn_mfma_f32_16x16x32_bf16(
                    af, wf[t], (f32x4){0.f, 0.f, 0.f, 0.f}, 0, 0, 0);

#pragma unroll
            for (int r = 0; r < 4; ++r) {
                const int ei = base + quad * 4 + r;
                if (ei < end) {
                    const int s = ssrc[ei];
                    const float* xrow = xin + (size_t)s * 64;
                    s0 += fmaxf(xrow[ 0 + row] + bias[0] + acc[0][r], 0.f);
                    s1 += fmaxf(xrow[16 + row] + bias[1] + acc[1][r], 0.f);
                    s2 += fmaxf(xrow[32 + row] + bias[2] + acc[2][r], 0.f);
                    s3 += fmaxf(xrow[48 + row] + bias[3] + acc[3][r], 0.f);
                }
            }
        }
        s0 += __shfl_xor(s0, 16); s0 += __shfl_xor(s0, 32);
        s1 += __shfl_xor(s1, 16); s1 += __shfl_xor(s1, 32);
        s2 += __shfl_xor(s2, 16); s2 += __shfl_xor(s2, 32);
        s3 += __shfl_xor(s3, 16); s3 += __shfl_xor(s3, 32);
        const float v = (quad == 0) ? s0 : (quad == 1) ? s1
                       : (quad == 2) ? s2 : s3;   // channel = lane
        const int pos = ((lane >> 2) & 3) * 16 + ((lane >> 4) & 3) * 4 + (lane & 3);
        agg[(size_t)n * 64 + pos] = v;
    }
}

// ---------------------------------------------------------------------------
// Node MLP via MFMA (one wave = 16 nodes), per-wave LDS transpose.
// agg is read with the bit-pair-swapped block permutation.
// ---------------------------------------------------------------------------
#define LSTRIDE 68

__global__ __launch_bounds__(256) void gine_node_mfma(
    const float* __restrict__ xin, const float* __restrict__ agg,
    const float* __restrict__ w1, const float* __restrict__ b1,
    const float* __restrict__ w2, const float* __restrict__ b2,
    float* __restrict__ hout)
{
    __shared__ float lds[4][16 * LSTRIDE];
    const int lane = threadIdx.x & 63;
    const int c = lane & 15, q = lane >> 4;
    float* L = lds[threadIdx.x >> 6];

    const int gwave  = (blockIdx.x * blockDim.x + threadIdx.x) >> 6;
    const int nwaves = (gridDim.x * blockDim.x) >> 6;

    bf16x8 a1[4][2], a2[4][2];
#pragma unroll
    for (int mt = 0; mt < 4; ++mt)
#pragma unroll
        for (int ks = 0; ks < 2; ++ks) {
            ushort8 u1, u2;
#pragma unroll
            for (int j = 0; j < 8; ++j) {
                const int k = ks * 32 + q * 8 + j;
                u1[j] = f2bf(w1[k * 64 + mt * 16 + c]);
                u2[j] = f2bf(w2[k * 64 + mt * 16 + c]);
            }
            a1[mt][ks] = __builtin_bit_cast(bf16x8, u1);
            a2[mt][ks] = __builtin_bit_cast(bf16x8, u2);
        }
    f32x4 b1v[4], b2v[4];
#pragma unroll
    for (int mt = 0; mt < 4; ++mt) {
        b1v[mt] = *(const f32x4*)(b1 + mt * 16 + q * 4);
        b2v[mt] = *(const f32x4*)(b2 + mt * 16 + q * 4);
    }

    const int ntiles = N_NODES / 16;
    for (int tile = gwave; tile < ntiles; tile += nwaves) {
        const int n0 = tile * 16;
        const float* xr = xin + (size_t)(n0 + c) * 64;
        const float* ar = agg + (size_t)(n0 + c) * 64;

        bf16x8 hb[2];
#pragma unroll
        for (int ks = 0; ks < 2; ++ks) {
            const int o = ks * 32 + q * 8;
            const int b0 = o >> 2, b1i = b0 + 1;
            const float4 xa = *(const float4*)(xr + o);
            const float4 xb = *(const float4*)(xr + o + 4);
            const float4 aa = *(const float4*)(ar + ((b0 & 3) * 16 + (b0 >> 2) * 4));
            const float4 ab = *(const float4*)(ar + ((b1i & 3) * 16 + (b1i >> 2) * 4));
            ushort8 u;
            u[0] = f2bf(xa.x + aa.x); u[1] = f2bf(xa.y + aa.y);
            u[2] = f2bf(xa.z + aa.z); u[3] = f2bf(xa.w + aa.w);
            u[4] = f2bf(xb.x + ab.x); u[5] = f2bf(xb.y + ab.y);
            u[6] = f2bf(xb.z + ab.z); u[7] = f2bf(xb.w + ab.w);
            hb[ks] = __builtin_bit_cast(bf16x8, u);
        }

        f32x4 acc[4];
#pragma unroll
        for (int mt = 0; mt < 4; ++mt) {
            acc[mt] = __builtin_amdgcn_mfma_f32_16x16x32_bf16(
                a1[mt][0], hb[0], (f32x4){0.f, 0.f, 0.f, 0.f}, 0, 0, 0);
            acc[mt] = __builtin_amdgcn_mfma_f32_16x16x32_bf16(
                a1[mt][1], hb[1], acc[mt], 0, 0, 0);
        }

#pragma unroll
        for (int mt = 0; mt < 4; ++mt) {
            f32x4 t;
#pragma unroll
            for (int r = 0; r < 4; ++r) t[r] = fmaxf(acc[mt][r] + b1v[mt][r], 0.f);
            *(f32x4*)(L + c * LSTRIDE + mt * 16 + q * 4) = t;
        }
        asm volatile("s_waitcnt lgkmcnt(0)" ::: "memory");

        bf16x8 tb[2];
#pragma unroll
        for (int ks = 0; ks < 2; ++ks) {
            const f32x4 lo = *(const f32x4*)(L + c * LSTRIDE + ks * 32 + q * 8);
            const f32x4 hi = *(const f32x4*)(L + c * LSTRIDE + ks * 32 + q * 8 + 4);
            ushort8 u;
            u[0] = f2bf(lo[0]); u[1] = f2bf(lo[1]); u[2] = f2bf(lo[2]); u[3] = f2bf(lo[3]);
            u[4] = f2bf(hi[0]); u[5] = f2bf(hi[1]); u[6] = f2bf(hi[2]); u[7] = f2bf(hi[3]);
            tb[ks] = __builtin_bit_cast(bf16x8, u);
        }
        asm volatile("s_waitcnt lgkmcnt(0)" ::: "memory");

#pragma unroll
        for (int mt = 0; mt < 4; ++mt) {
            acc[mt] = __builtin_amdgcn_mfma_f32_16x16x32_bf16(
                a2[mt][0], tb[0], (f32x4){0.f, 0.f, 0.f, 0.f}, 0, 0, 0);
            acc[mt] = __builtin_amdgcn_mfma_f32_16x16x32_bf16(
                a2[mt][1], tb[1], acc[mt], 0, 0, 0);
        }

        float* hr = hout + (size_t)(n0 + c) * 64;
#pragma unroll
        for (int mt = 0; mt < 4; ++mt) {
            f32x4 u;
#pragma unroll
            for (int r = 0; r < 4; ++r) u[r] = fmaxf(acc[mt][r] + b2v[mt][r], 0.f);
            *(f32x4*)(hr + mt * 16 + q * 4) = u;
        }
    }
}

__global__ __launch_bounds__(256) void gine_node_head_mfma(
    const float* __restrict__ xin, const float* __restrict__ agg,
    const float* __restrict__ w1, const float* __restrict__ b1,
    const float* __restrict__ w2, const float* __restrict__ b2,
    const float* __restrict__ hw, const float* __restrict__ hbp,
    float* __restrict__ outp)
{
    __shared__ float lds[4][16 * LSTRIDE];
    const int lane = threadIdx.x & 63;
    const int c = lane & 15, q = lane >> 4;
    float* L = lds[threadIdx.x >> 6];

    const int gwave  = (blockIdx.x * blockDim.x + threadIdx.x) >> 6;
    const int nwaves = (gridDim.x * blockDim.x) >> 6;

    bf16x8 a1[4][2], a2[4][2], a3[2][2];
#pragma unroll
    for (int mt = 0; mt < 4; ++mt)
#pragma unroll
        for (int ks = 0; ks < 2; ++ks) {
            ushort8 u1, u2;
#pragma unroll
            for (int j = 0; j < 8; ++j) {
                const int k = ks * 32 + q * 8 + j;
                u1[j] = f2bf(w1[k * 64 + mt * 16 + c]);
                u2[j] = f2bf(w2[k * 64 + mt * 16 + c]);
            }
            a1[mt][ks] = __builtin_bit_cast(bf16x8, u1);
            a2[mt][ks] = __builtin_bit_cast(bf16x8, u2);
        }
#pragma unroll
    for (int mt = 0; mt < 2; ++mt)
#pragma unroll
        for (int ks = 0; ks < 2; ++ks) {
            ushort8 u3;
#pragma unroll
            for (int j = 0; j < 8; ++j) {
                const int k = ks * 32 + q * 8 + j;
                u3[j] = f2bf(hw[k * 32 + mt * 16 + c]);
            }
            a3[mt][ks] = __builtin_bit_cast(bf16x8, u3);
        }
    f32x4 b1v[4], b2v[4], hbv[2];
#pragma unroll
    for (int mt = 0; mt < 4; ++mt) {
        b1v[mt] = *(const f32x4*)(b1 + mt * 16 + q * 4);
        b2v[mt] = *(const f32x4*)(b2 + mt * 16 + q * 4);
    }
#pragma unroll
    for (int mt = 0; mt < 2; ++mt)
        hbv[mt] = *(const f32x4*)(hbp + mt * 16 + q * 4);

    const int ntiles = N_NODES / 16;
    for (int tile = gwave; tile < ntiles; tile += nwaves) {
        const int n0 = tile * 16;
        const float* xr = xin + (size_t)(n0 + c) * 64;
        const float* ar = agg + (size_t)(n0 + c) * 64;

        bf16x8 hb[2];
#pragma unroll
        for (int ks = 0; ks < 2; ++ks) {
            const int o = ks * 32 + q * 8;
            const int b0 = o >> 2, b1i = b0 + 1;
            const float4 xa = *(const float4*)(xr + o);
            const float4 xb = *(const float4*)(xr + o + 4);
            const float4 aa = *(const float4*)(ar + ((b0 & 3) * 16 + (b0 >> 2) * 4));
            const float4 ab = *(const float4*)(ar + ((b1i & 3) * 16 + (b1i >> 2) * 4));
            ushort8 u;
            u[0] = f2bf(xa.x + aa.x); u[1] = f2bf(xa.y + aa.y);
            u[2] = f2bf(xa.z + aa.z); u[3] = f2bf(xa.w + aa.w);
            u[4] = f2bf(xb.x + ab.x); u[5] = f2bf(xb.y + ab.y);
            u[6] = f2bf(xb.z + ab.z); u[7] = f2bf(xb.w + ab.w);
            hb[ks] = __builtin_bit_cast(bf16x8, u);
        }

        f32x4 acc[4];
#pragma unroll
        for (int mt = 0; mt < 4; ++mt) {
            acc[mt] = __builtin_amdgcn_mfma_f32_16x16x32_bf16(
                a1[mt][0], hb[0], (f32x4){0.f, 0.f, 0.f, 0.f}, 0, 0, 0);
            acc[mt] = __builtin_amdgcn_mfma_f32_16x16x32_bf16(
                a1[mt][1], hb[1], acc[mt], 0, 0, 0);
        }

#pragma unroll
        for (int mt = 0; mt < 4; ++mt) {
            f32x4 t;
#pragma unroll
            for (int r = 0; r < 4; ++r) t[r] = fmaxf(acc[mt][r] + b1v[mt][r], 0.f);
            *(f32x4*)(L + c * LSTRIDE + mt * 16 + q * 4) = t;
        }
        asm volatile("s_waitcnt lgkmcnt(0)" ::: "memory");

        bf16x8 tb[2];
#pragma unroll
        for (int ks = 0; ks < 2; ++ks) {
            const f32x4 lo = *(const f32x4*)(L + c * LSTRIDE + ks * 32 + q * 8);
            const f32x4 hi = *(const f32x4*)(L + c * LSTRIDE + ks * 32 + q * 8 + 4);
            ushort8 u;
            u[0] = f2bf(lo[0]); u[1] = f2bf(lo[1]); u[2] = f2bf(lo[2]); u[3] = f2bf(lo[3]);
            u[4] = f2bf(hi[0]); u[5] = f2bf(hi[1]); u[6] = f2bf(hi[2]); u[7] = f2bf(hi[3]);
            tb[ks] = __builtin_bit_cast(bf16x8, u);
        }
        asm volatile("s_waitcnt lgkmcnt(0)" ::: "memory");

#pragma unroll
        for (int mt = 0; mt < 4; ++mt) {
            acc[mt] = __builtin_amdgcn_mfma_f32_16x16x32_bf16(
                a2[mt][0], tb[0], (f32x4){0.f, 0.f, 0.f, 0.f}, 0, 0, 0);
            acc[mt] = __builtin_amdgcn_mfma_f32_16x16x32_bf16(
                a2[mt][1], tb[1], acc[mt], 0, 0, 0);
        }

#pragma unroll
        for (int mt = 0; mt < 4; ++mt) {
            f32x4 t;
#pragma unroll
            for (int r = 0; r < 4; ++r) t[r] = fmaxf(acc[mt][r] + b2v[mt][r], 0.f);
            *(f32x4*)(L + c * LSTRIDE + mt * 16 + q * 4) = t;
        }
        asm volatile("s_waitcnt lgkmcnt(0)" ::: "memory");

        bf16x8 ub[2];
#pragma unroll
        for (int ks = 0; ks < 2; ++ks) {
            const f32x4 lo = *(const f32x4*)(L + c * LSTRIDE + ks * 32 + q * 8);
            const f32x4 hi = *(const f32x4*)(L + c * LSTRIDE + ks * 32 + q * 8 + 4);
            ushort8 u;
            u[0] = f2bf(lo[0]); u[1] = f2bf(lo[1]); u[2] = f2bf(lo[2]); u[3] = f2bf(lo[3]);
            u[4] = f2bf(hi[0]); u[5] = f2bf(hi[1]); u[6] = f2bf(hi[2]); u[7] = f2bf(hi[3]);
            ub[ks] = __builtin_bit_cast(bf16x8, u);
        }
        asm volatile("s_waitcnt lgkmcnt(0)" ::: "memory");

        f32x4 acc3[2];
#pragma unroll
        for (int mt = 0; mt < 2; ++mt) {
            acc3[mt] = __builtin_amdgcn_mfma_f32_16x16x32_bf16(
                a3[mt][0], ub[0], (f32x4){0.f, 0.f, 0.f, 0.f}, 0, 0, 0);
            acc3[mt] = __builtin_amdgcn_mfma_f32_16x16x32_bf16(
                a3[mt][1], ub[1], acc3[mt], 0, 0, 0);
        }

        float* outr = outp + (size_t)(n0 + c) * 32;
#pragma unroll
        for (int mt = 0; mt < 2; ++mt) {
            f32x4 u;
#pragma unroll
            for (int r = 0; r < 4; ++r) u[r] = acc3[mt][r] + hbv[mt][r];
            *(f32x4*)(outr + mt * 16 + q * 4) = u;
        }
    }
}

extern "C" void kernel_launch(void* const* d_in, const int* in_sizes, int n_in,
                              void* d_out, int out_size, void* d_ws, size_t ws_size,
                              hipStream_t stream) {
    const float* x     = (const float*)d_in[0];
    const float* ea    = (const float*)d_in[1];
    const int*   ei    = (const int*)  d_in[2];
    const float* c1lw  = (const float*)d_in[3];
    const float* c1lb  = (const float*)d_in[4];
    const float* c1w1  = (const float*)d_in[5];
    const float* c1b1  = (const float*)d_in[6];
    const float* c1w2  = (const float*)d_in[7];
    const float* c1b2  = (const float*)d_in[8];
    const float* c2lw  = (const float*)d_in[9];
    const float* c2lb  = (const float*)d_in[10];
    const float* c2w1  = (const float*)d_in[11];
    const float* c2b1  = (const float*)d_in[12];
    const float* c2w2  = (const float*)d_in[13];
    const float* c2b2  = (const float*)d_in[14];
    const float* hw    = (const float*)d_in[15];
    const float* hb    = (const float*)d_in[16];

    const int* srcp = ei;
    const int* dstp = ei + N_EDGES;

    float* agg  = (float*)d_ws;                       // [N,64]
    float* h1   = agg + (size_t)N_NODES * 64;         // [N,64]
    int*   cnt  = (int*)(h1 + (size_t)N_NODES * 64);  // [N]
    int*   offs = cnt + N_NODES;                      // [N+1]
    int*   runc = offs + (N_NODES + 1);               // [N] (fallback only)
    int*   bsum = runc + N_NODES;                     // [256]
    int*   bpre = bsum + 256;                         // [256]
    int*   ssrc = bpre + 256;                         // [E]
    int*   rank = ssrc + N_EDGES;                     // [E]
    size_t tail_off = ((size_t)((char*)(rank + N_EDGES) - (char*)d_ws) + 63) & ~(size_t)63;
    unsigned short* ea_s = (unsigned short*)((char*)d_ws + tail_off);   // [E,32] bf16
    int*            perm_tail = (int*)((char*)d_ws + tail_off);         // fallback [E]
    const bool primary = ws_size >= tail_off + (size_t)N_EDGES * 32 * sizeof(unsigned short) + 64;

    // primary: perm aliases h1 (only needed before h1 is written)
    int* perm = primary ? (int*)h1 : perm_tail;

    float* outp = (float*)d_out;
    const int SCAN_G = (N_NODES + 255) / 256;

    hipMemsetAsync(cnt, 0, N_NODES * sizeof(int), stream);
    hipLaunchKernelGGL(csr_hist_rank, dim3(2048), dim3(256), 0, stream, dstp, cnt, rank);
    // scan_p1 at 256 blocks writes zeros past N (replaces bsum memset)
    hipLaunchKernelGGL(scan_p1, dim3(256),    dim3(256), 0, stream, cnt, bsum);
    hipLaunchKernelGGL(scan_p2, dim3(1),      dim3(256), 0, stream, bsum, bpre, offs);
    hipLaunchKernelGGL(scan_p3, dim3(SCAN_G), dim3(256), 0, stream, cnt, bpre, offs);

    if (primary) {
        hipLaunchKernelGGL(csr_scatter_perm_rank, dim3(2048), dim3(256), 0, stream,
                           dstp, rank, offs, perm);
        hipLaunchKernelGGL(csr_permute_ea, dim3(4096), dim3(256), 0, stream,
                           ea, srcp, perm, ssrc, ea_s);
        hipLaunchKernelGGL(gine_gather_bf, dim3(4096), dim3(256), 0, stream,
                           x, ea_s, ssrc, offs, c1lw, c1lb, agg);
        hipLaunchKernelGGL(gine_node_mfma, dim3(800), dim3(256), 0, stream,
                           x, agg, c1w1, c1b1, c1w2, c1b2, h1);
        hipLaunchKernelGGL(gine_gather_bf, dim3(4096), dim3(256), 0, stream,
                           h1, ea_s, ssrc, offs, c2lw, c2lb, agg);
        hipLaunchKernelGGL(gine_node_head_mfma, dim3(800), dim3(256), 0, stream,
                           h1, agg, c2w1, c2b1, c2w2, c2b2, hw, hb, outp);
    } else {
        hipMemsetAsync(runc, 0, N_NODES * sizeof(int), stream);
        hipLaunchKernelGGL(csr_scatter, dim3(1024), dim3(256), 0, stream,
                           srcp, dstp, offs, runc, perm, ssrc);
        hipLaunchKernelGGL(gine_gather_fp32, dim3(4096), dim3(256), 0, stream,
                           x, ea, perm, ssrc, offs, c1lw, c1lb, agg);
        hipLaunchKernelGGL(gine_node_mfma, dim3(800), dim3(256), 0, stream,
                           x, agg, c1w1, c1b1, c1w2, c1b2, h1);
        hipLaunchKernelGGL(gine_gather_fp32, dim3(4096), dim3(256), 0, stream,
                           h1, ea, perm, ssrc, offs, c2lw, c2lb, agg);
        hipLaunchKernelGGL(gine_node_head_mfma, dim3(800), dim3(256), 0, stream,
                           h1, agg, c2w1, c2b1, c2w2, c2b2, hw, hb, outp);
    }
}

// Round 8
// 378.279 us; speedup vs baseline: 1.5619x; 1.0175x over previous
//
#include <hip/hip_runtime.h>

#define N_NODES 50000
#define N_EDGES 800000

typedef __bf16 bf16x8 __attribute__((ext_vector_type(8)));
typedef unsigned short ushort8 __attribute__((ext_vector_type(8)));
typedef unsigned short u16x4 __attribute__((ext_vector_type(4)));
typedef float f32x4 __attribute__((ext_vector_type(4)));

__device__ __forceinline__ unsigned short f2bf(float f) {
    unsigned u = __builtin_bit_cast(unsigned, f);
    u += 0x7fffu + ((u >> 16) & 1u);
    return (unsigned short)(u >> 16);
}
__device__ __forceinline__ float bf2f(unsigned short u) {
    return __builtin_bit_cast(float, (unsigned)u << 16);
}

__device__ __forceinline__ f32x4 shfl_xor4(f32x4 v, int m) {
    f32x4 r;
    r[0] = __shfl_xor(v[0], m); r[1] = __shfl_xor(v[1], m);
    r[2] = __shfl_xor(v[2], m); r[3] = __shfl_xor(v[3], m);
    return r;
}
__device__ __forceinline__ f32x4 sel4(bool p, f32x4 a, f32x4 b) {
    f32x4 r;
    r[0] = p ? a[0] : b[0]; r[1] = p ? a[1] : b[1];
    r[2] = p ? a[2] : b[2]; r[3] = p ? a[3] : b[3];
    return r;
}

// Permuted channel order (for agg fp32, x_bf, h1_bf):
//   pos(ch) = ch[3:2]<<4 | ch[5:4]<<2 | ch[1:0]
// so a gather lane (q) finds its 16 channels {mt*16+q*4+r} contiguously at
// pos = q*16 + mt*4 + r (32B = 2x16B bf16 loads per row).

// ---------------------------------------------------------------------------
// CSR build: hist(+rank) -> 3-phase scan -> atomic-free perm scatter -> permute
// ---------------------------------------------------------------------------
__global__ __launch_bounds__(256) void csr_hist_rank(const int* __restrict__ dstp,
                                                     int* __restrict__ cnt,
                                                     int* __restrict__ rank) {
    for (int e = blockIdx.x * blockDim.x + threadIdx.x; e < N_EDGES;
         e += gridDim.x * blockDim.x)
        rank[e] = atomicAdd(&cnt[dstp[e]], 1);
}

// launched with 256 blocks; blocks past N write 0 (replaces bsum memset)
__global__ __launch_bounds__(256) void scan_p1(const int* __restrict__ cnt,
                                               int* __restrict__ bsum) {
    __shared__ int sm[256];
    const int t = threadIdx.x;
    const int idx = blockIdx.x * 256 + t;
    sm[t] = (idx < N_NODES) ? cnt[idx] : 0;
    __syncthreads();
    for (int off = 128; off > 0; off >>= 1) {
        if (t < off) sm[t] += sm[t + off];
        __syncthreads();
    }
    if (t == 0) bsum[blockIdx.x] = sm[0];
}

__global__ __launch_bounds__(256) void scan_p2(const int* __restrict__ bsum,
                                               int* __restrict__ bpre,
                                               int* __restrict__ offs) {
    __shared__ int sm[256];
    const int t = threadIdx.x;
    int v = bsum[t];
    sm[t] = v;
    __syncthreads();
    for (int off = 1; off < 256; off <<= 1) {
        int u = (t >= off) ? sm[t - off] : 0;
        __syncthreads();
        sm[t] += u;
        __syncthreads();
    }
    bpre[t] = sm[t] - v;
    if (t == 255) offs[N_NODES] = sm[255];
}

__global__ __launch_bounds__(256) void scan_p3(const int* __restrict__ cnt,
                                               const int* __restrict__ bpre,
                                               int* __restrict__ offs) {
    __shared__ int sm[256];
    const int t = threadIdx.x;
    const int idx = blockIdx.x * 256 + t;
    const int v = (idx < N_NODES) ? cnt[idx] : 0;
    sm[t] = v;
    __syncthreads();
    for (int off = 1; off < 256; off <<= 1) {
        int u = (t >= off) ? sm[t - off] : 0;
        __syncthreads();
        sm[t] += u;
        __syncthreads();
    }
    if (idx < N_NODES) offs[idx] = bpre[blockIdx.x] + sm[t] - v;
}

__global__ __launch_bounds__(256) void csr_scatter_perm_rank(
    const int* __restrict__ dstp, const int* __restrict__ rank,
    const int* __restrict__ offs, int* __restrict__ perm) {
    for (int e = blockIdx.x * blockDim.x + threadIdx.x; e < N_EDGES;
         e += gridDim.x * blockDim.x)
        perm[offs[dstp[e]] + rank[e]] = e;
}

// gather-style permute: coalesced writes, whole-line random ea reads
__global__ __launch_bounds__(256) void csr_permute_ea(
    const float* __restrict__ ea, const int* __restrict__ srcp,
    const int* __restrict__ perm, int* __restrict__ ssrc,
    unsigned short* __restrict__ ea_s) {
    for (int p = blockIdx.x * blockDim.x + threadIdx.x; p < N_EDGES;
         p += gridDim.x * blockDim.x) {
        const int e = perm[p];
        ssrc[p] = srcp[e];
        const float* er = ea + (size_t)e * 32;
        unsigned short* op = ea_s + (size_t)p * 32;
#pragma unroll
        for (int sgm = 0; sgm < 4; ++sgm) {
            const float4 v0 = *(const float4*)(er + sgm * 8);
            const float4 v1 = *(const float4*)(er + sgm * 8 + 4);
            ushort8 u;
            u[0] = f2bf(v0.x); u[1] = f2bf(v0.y); u[2] = f2bf(v0.z); u[3] = f2bf(v0.w);
            u[4] = f2bf(v1.x); u[5] = f2bf(v1.y); u[6] = f2bf(v1.z); u[7] = f2bf(v1.w);
            *(ushort8*)(op + sgm * 8) = u;
        }
    }
}

// x fp32 [N,64] -> bf16 in permuted channel order
__global__ __launch_bounds__(256) void x_to_bf(const float* __restrict__ x,
                                               unsigned short* __restrict__ xbf) {
    for (int i = blockIdx.x * blockDim.x + threadIdx.x; i < N_NODES * 16;
         i += gridDim.x * blockDim.x) {
        const int n = i >> 4, b = i & 15;          // b = ch>>2
        const float4 v = *(const float4*)(x + (size_t)n * 64 + b * 4);
        u16x4 o;
        o[0] = f2bf(v.x); o[1] = f2bf(v.y); o[2] = f2bf(v.z); o[3] = f2bf(v.w);
        *(u16x4*)(xbf + (size_t)n * 64 + (b & 3) * 16 + (b >> 2) * 4) = o;
    }
}

// ---------------------------------------------------------------------------
// Gather (primary), transposed MFMA: D[m=channel][n=edge]; lane (q, c) owns
// edge (base+c), channels {mt*16+q*4+r}. x gather = 2x16B bf16 loads/lane
// (permuted layout: one 128B line per row). Bias in MFMA C operand.
// Whole-node src prefetch + __shfl. 15-shuffle merging butterfly; agg stored
// in permuted order at position lane.
// ---------------------------------------------------------------------------
__global__ __launch_bounds__(256) void gine_gather_bf(
    const unsigned short* __restrict__ xbf,   // [N,64] bf16 permuted
    const unsigned short* __restrict__ eas,   // [E,32] bf16 dst-sorted
    const int*   __restrict__ ssrc,
    const int*   __restrict__ offs,
    const float* __restrict__ linW,
    const float* __restrict__ linB,
    float*       __restrict__ agg)            // [N,64] fp32 permuted
{
    const int lane = threadIdx.x & 63;
    const int gwave  = (blockIdx.x * blockDim.x + threadIdx.x) >> 6;
    const int nwaves = (gridDim.x * blockDim.x) >> 6;
    const int c = lane & 15;
    const int q = lane >> 4;

    bf16x8 wf[4];
#pragma unroll
    for (int mt = 0; mt < 4; ++mt) {
        ushort8 us;
#pragma unroll
        for (int j = 0; j < 8; ++j)
            us[j] = f2bf(linW[(q * 8 + j) * 64 + mt * 16 + c]);
        wf[mt] = __builtin_bit_cast(bf16x8, us);
    }
    f32x4 biasv[4];
#pragma unroll
    for (int mt = 0; mt < 4; ++mt)
        biasv[mt] = *(const f32x4*)(linB + mt * 16 + q * 4);

    for (int n = gwave; n < N_NODES; n += nwaves) {
        const int start = offs[n];
        const int end   = offs[n + 1];

        const int pidx = (start + lane < end) ? (start + lane)
                                              : ((end > start) ? end - 1 : 0);
        const int sl = ssrc[pidx];

        f32x4 s0 = {0.f,0.f,0.f,0.f}, s1 = {0.f,0.f,0.f,0.f};
        f32x4 s2 = {0.f,0.f,0.f,0.f}, s3 = {0.f,0.f,0.f,0.f};

        int t = 0;
        for (int base = start; base < end; base += 16, ++t) {
            const int eidx = base + c;
            const bool valid = eidx < end;
            const int ecl = valid ? eidx : end - 1;

            const bf16x8 bf = __builtin_bit_cast(bf16x8,
                *(const ushort8*)(eas + (size_t)ecl * 32 + q * 8));

            int s;
            if (t < 4) s = __shfl(sl, (t << 4) + c);
            else       s = ssrc[ecl];

            f32x4 acc[4];
            acc[0] = __builtin_amdgcn_mfma_f32_16x16x32_bf16(wf[0], bf, biasv[0], 0, 0, 0);
            acc[1] = __builtin_amdgcn_mfma_f32_16x16x32_bf16(wf[1], bf, biasv[1], 0, 0, 0);
            acc[2] = __builtin_amdgcn_mfma_f32_16x16x32_bf16(wf[2], bf, biasv[2], 0, 0, 0);
            acc[3] = __builtin_amdgcn_mfma_f32_16x16x32_bf16(wf[3], bf, biasv[3], 0, 0, 0);

            // x row: 32B contiguous per lane (channels mt*4+r at pos q*16+..)
            const unsigned short* xr = xbf + (size_t)s * 64 + q * 16;
            const ushort8 xa = *(const ushort8*)xr;
            const ushort8 xb = *(const ushort8*)(xr + 8);

            const float NEG = -3.0e38f;
#pragma unroll
            for (int r = 0; r < 4; ++r) {
                s0[r] += fmaxf((valid ? bf2f(xa[r])     : NEG) + acc[0][r], 0.f);
                s1[r] += fmaxf((valid ? bf2f(xa[4 + r]) : NEG) + acc[1][r], 0.f);
                s2[r] += fmaxf((valid ? bf2f(xb[r])     : NEG) + acc[2][r], 0.f);
                s3[r] += fmaxf((valid ? bf2f(xb[4 + r]) : NEG) + acc[3][r], 0.f);
            }
        }

        f32x4 t0 = sel4((c & 8) != 0, s2, s0) + shfl_xor4(sel4((c & 8) != 0, s0, s2), 8);
        f32x4 t1 = sel4((c & 8) != 0, s3, s1) + shfl_xor4(sel4((c & 8) != 0, s1, s3), 8);
        f32x4 u = sel4((c & 4) != 0, t1, t0) + shfl_xor4(sel4((c & 4) != 0, t0, t1), 4);
        float v0 = ((c & 2) ? u[2] : u[0]) + __shfl_xor((c & 2) ? u[0] : u[2], 2);
        float v1 = ((c & 2) ? u[3] : u[1]) + __shfl_xor((c & 2) ? u[1] : u[3], 2);
        float w = ((c & 1) ? v1 : v0) + __shfl_xor((c & 1) ? v0 : v1, 1);

        agg[(size_t)n * 64 + lane] = w;
    }
}

// fallback gather: same structure, ea fp32 via perm (random reads)
__global__ __launch_bounds__(256) void gine_gather_fb(
    const unsigned short* __restrict__ xbf, const float* __restrict__ ea,
    const int* __restrict__ perm, const int* __restrict__ ssrc,
    const int* __restrict__ offs, const float* __restrict__ linW,
    const float* __restrict__ linB, float* __restrict__ agg)
{
    const int lane = threadIdx.x & 63;
    const int gwave  = (blockIdx.x * blockDim.x + threadIdx.x) >> 6;
    const int nwaves = (gridDim.x * blockDim.x) >> 6;
    const int c = lane & 15;
    const int q = lane >> 4;

    bf16x8 wf[4];
#pragma unroll
    for (int mt = 0; mt < 4; ++mt) {
        ushort8 us;
#pragma unroll
        for (int j = 0; j < 8; ++j)
            us[j] = f2bf(linW[(q * 8 + j) * 64 + mt * 16 + c]);
        wf[mt] = __builtin_bit_cast(bf16x8, us);
    }
    f32x4 biasv[4];
#pragma unroll
    for (int mt = 0; mt < 4; ++mt)
        biasv[mt] = *(const f32x4*)(linB + mt * 16 + q * 4);

    for (int n = gwave; n < N_NODES; n += nwaves) {
        const int start = offs[n];
        const int end   = offs[n + 1];
        const int pidx = (start + lane < end) ? (start + lane)
                                              : ((end > start) ? end - 1 : 0);
        const int sl = ssrc[pidx];

        f32x4 s0 = {0.f,0.f,0.f,0.f}, s1 = {0.f,0.f,0.f,0.f};
        f32x4 s2 = {0.f,0.f,0.f,0.f}, s3 = {0.f,0.f,0.f,0.f};

        int t = 0;
        for (int base = start; base < end; base += 16, ++t) {
            const int eidx = base + c;
            const bool valid = eidx < end;
            const int ecl = valid ? eidx : end - 1;

            const int e = perm[ecl];
            const float* ap = ea + (size_t)e * 32 + q * 8;
            const float4 a0 = *(const float4*)ap;
            const float4 a1 = *(const float4*)(ap + 4);
            ushort8 ub;
            ub[0] = f2bf(a0.x); ub[1] = f2bf(a0.y); ub[2] = f2bf(a0.z); ub[3] = f2bf(a0.w);
            ub[4] = f2bf(a1.x); ub[5] = f2bf(a1.y); ub[6] = f2bf(a1.z); ub[7] = f2bf(a1.w);
            const bf16x8 bf = __builtin_bit_cast(bf16x8, ub);

            int s;
            if (t < 4) s = __shfl(sl, (t << 4) + c);
            else       s = ssrc[ecl];

            f32x4 acc[4];
            acc[0] = __builtin_amdgcn_mfma_f32_16x16x32_bf16(wf[0], bf, biasv[0], 0, 0, 0);
            acc[1] = __builtin_amdgcn_mfma_f32_16x16x32_bf16(wf[1], bf, biasv[1], 0, 0, 0);
            acc[2] = __builtin_amdgcn_mfma_f32_16x16x32_bf16(wf[2], bf, biasv[2], 0, 0, 0);
            acc[3] = __builtin_amdgcn_mfma_f32_16x16x32_bf16(wf[3], bf, biasv[3], 0, 0, 0);

            const unsigned short* xr = xbf + (size_t)s * 64 + q * 16;
            const ushort8 xa = *(const ushort8*)xr;
            const ushort8 xb = *(const ushort8*)(xr + 8);

            const float NEG = -3.0e38f;
#pragma unroll
            for (int r = 0; r < 4; ++r) {
                s0[r] += fmaxf((valid ? bf2f(xa[r])     : NEG) + acc[0][r], 0.f);
                s1[r] += fmaxf((valid ? bf2f(xa[4 + r]) : NEG) + acc[1][r], 0.f);
                s2[r] += fmaxf((valid ? bf2f(xb[r])     : NEG) + acc[2][r], 0.f);
                s3[r] += fmaxf((valid ? bf2f(xb[4 + r]) : NEG) + acc[3][r], 0.f);
            }
        }

        f32x4 t0 = sel4((c & 8) != 0, s2, s0) + shfl_xor4(sel4((c & 8) != 0, s0, s2), 8);
        f32x4 t1 = sel4((c & 8) != 0, s3, s1) + shfl_xor4(sel4((c & 8) != 0, s1, s3), 8);
        f32x4 u = sel4((c & 4) != 0, t1, t0) + shfl_xor4(sel4((c & 4) != 0, t0, t1), 4);
        float v0 = ((c & 2) ? u[2] : u[0]) + __shfl_xor((c & 2) ? u[0] : u[2], 2);
        float v1 = ((c & 2) ? u[3] : u[1]) + __shfl_xor((c & 2) ? u[1] : u[3], 2);
        float w = ((c & 1) ? v1 : v0) + __shfl_xor((c & 1) ? v0 : v1, 1);

        agg[(size_t)n * 64 + lane] = w;
    }
}

// ---------------------------------------------------------------------------
// Node MLP via MFMA (one wave = 16 nodes), per-wave LDS transpose.
// conv1: xin fp32 + agg(permuted fp32) -> h1 written as permuted bf16.
// ---------------------------------------------------------------------------
#define LSTRIDE 68

__global__ __launch_bounds__(256) void gine_node_mfma(
    const float* __restrict__ xin, const float* __restrict__ agg,
    const float* __restrict__ w1, const float* __restrict__ b1,
    const float* __restrict__ w2, const float* __restrict__ b2,
    unsigned short* __restrict__ hbf)          // [N,64] bf16 permuted
{
    __shared__ float lds[4][16 * LSTRIDE];
    const int lane = threadIdx.x & 63;
    const int c = lane & 15, q = lane >> 4;
    float* L = lds[threadIdx.x >> 6];

    const int gwave  = (blockIdx.x * blockDim.x + threadIdx.x) >> 6;
    const int nwaves = (gridDim.x * blockDim.x) >> 6;

    bf16x8 a1[4][2], a2[4][2];
#pragma unroll
    for (int mt = 0; mt < 4; ++mt)
#pragma unroll
        for (int ks = 0; ks < 2; ++ks) {
            ushort8 u1, u2;
#pragma unroll
            for (int j = 0; j < 8; ++j) {
                const int k = ks * 32 + q * 8 + j;
                u1[j] = f2bf(w1[k * 64 + mt * 16 + c]);
                u2[j] = f2bf(w2[k * 64 + mt * 16 + c]);
            }
            a1[mt][ks] = __builtin_bit_cast(bf16x8, u1);
            a2[mt][ks] = __builtin_bit_cast(bf16x8, u2);
        }
    f32x4 b1v[4], b2v[4];
#pragma unroll
    for (int mt = 0; mt < 4; ++mt) {
        b1v[mt] = *(const f32x4*)(b1 + mt * 16 + q * 4);
        b2v[mt] = *(const f32x4*)(b2 + mt * 16 + q * 4);
    }

    const int ntiles = N_NODES / 16;
    for (int tile = gwave; tile < ntiles; tile += nwaves) {
        const int n0 = tile * 16;
        const float* xr = xin + (size_t)(n0 + c) * 64;
        const float* ar = agg + (size_t)(n0 + c) * 64;

        bf16x8 hb[2];
#pragma unroll
        for (int ks = 0; ks < 2; ++ks) {
            const int o = ks * 32 + q * 8;
            const int b0 = o >> 2, b1i = b0 + 1;
            const float4 xa = *(const float4*)(xr + o);
            const float4 xb = *(const float4*)(xr + o + 4);
            const float4 aa = *(const float4*)(ar + ((b0 & 3) * 16 + (b0 >> 2) * 4));
            const float4 ab = *(const float4*)(ar + ((b1i & 3) * 16 + (b1i >> 2) * 4));
            ushort8 u;
            u[0] = f2bf(xa.x + aa.x); u[1] = f2bf(xa.y + aa.y);
            u[2] = f2bf(xa.z + aa.z); u[3] = f2bf(xa.w + aa.w);
            u[4] = f2bf(xb.x + ab.x); u[5] = f2bf(xb.y + ab.y);
            u[6] = f2bf(xb.z + ab.z); u[7] = f2bf(xb.w + ab.w);
            hb[ks] = __builtin_bit_cast(bf16x8, u);
        }

        f32x4 acc[4];
#pragma unroll
        for (int mt = 0; mt < 4; ++mt) {
            acc[mt] = __builtin_amdgcn_mfma_f32_16x16x32_bf16(
                a1[mt][0], hb[0], (f32x4){0.f, 0.f, 0.f, 0.f}, 0, 0, 0);
            acc[mt] = __builtin_amdgcn_mfma_f32_16x16x32_bf16(
                a1[mt][1], hb[1], acc[mt], 0, 0, 0);
        }

#pragma unroll
        for (int mt = 0; mt < 4; ++mt) {
            f32x4 t;
#pragma unroll
            for (int r = 0; r < 4; ++r) t[r] = fmaxf(acc[mt][r] + b1v[mt][r], 0.f);
            *(f32x4*)(L + c * LSTRIDE + mt * 16 + q * 4) = t;
        }
        asm volatile("s_waitcnt lgkmcnt(0)" ::: "memory");

        bf16x8 tb[2];
#pragma unroll
        for (int ks = 0; ks < 2; ++ks) {
            const f32x4 lo = *(const f32x4*)(L + c * LSTRIDE + ks * 32 + q * 8);
            const f32x4 hi = *(const f32x4*)(L + c * LSTRIDE + ks * 32 + q * 8 + 4);
            ushort8 u;
            u[0] = f2bf(lo[0]); u[1] = f2bf(lo[1]); u[2] = f2bf(lo[2]); u[3] = f2bf(lo[3]);
            u[4] = f2bf(hi[0]); u[5] = f2bf(hi[1]); u[6] = f2bf(hi[2]); u[7] = f2bf(hi[3]);
            tb[ks] = __builtin_bit_cast(bf16x8, u);
        }
        asm volatile("s_waitcnt lgkmcnt(0)" ::: "memory");

#pragma unroll
        for (int mt = 0; mt < 4; ++mt) {
            acc[mt] = __builtin_amdgcn_mfma_f32_16x16x32_bf16(
                a2[mt][0], tb[0], (f32x4){0.f, 0.f, 0.f, 0.f}, 0, 0, 0);
            acc[mt] = __builtin_amdgcn_mfma_f32_16x16x32_bf16(
                a2[mt][1], tb[1], acc[mt], 0, 0, 0);
        }

        // h1 store: permuted bf16, lane's 16 channels contiguous at q*16
        unsigned short* hr = hbf + (size_t)(n0 + c) * 64 + q * 16;
        ushort8 lo8, hi8;
#pragma unroll
        for (int r = 0; r < 4; ++r) {
            lo8[r]     = f2bf(fmaxf(acc[0][r] + b2v[0][r], 0.f));
            lo8[4 + r] = f2bf(fmaxf(acc[1][r] + b2v[1][r], 0.f));
            hi8[r]     = f2bf(fmaxf(acc[2][r] + b2v[2][r], 0.f));
            hi8[4 + r] = f2bf(fmaxf(acc[3][r] + b2v[3][r], 0.f));
        }
        *(ushort8*)hr = lo8;
        *(ushort8*)(hr + 8) = hi8;
    }
}

// conv2 + head: xin is permuted bf16 h1
__global__ __launch_bounds__(256) void gine_node_head_mfma(
    const unsigned short* __restrict__ xbf, const float* __restrict__ agg,
    const float* __restrict__ w1, const float* __restrict__ b1,
    const float* __restrict__ w2, const float* __restrict__ b2,
    const float* __restrict__ hw, const float* __restrict__ hbp,
    float* __restrict__ outp)
{
    __shared__ float lds[4][16 * LSTRIDE];
    const int lane = threadIdx.x & 63;
    const int c = lane & 15, q = lane >> 4;
    float* L = lds[threadIdx.x >> 6];

    const int gwave  = (blockIdx.x * blockDim.x + threadIdx.x) >> 6;
    const int nwaves = (gridDim.x * blockDim.x) >> 6;

    bf16x8 a1[4][2], a2[4][2], a3[2][2];
#pragma unroll
    for (int mt = 0; mt < 4; ++mt)
#pragma unroll
        for (int ks = 0; ks < 2; ++ks) {
            ushort8 u1, u2;
#pragma unroll
            for (int j = 0; j < 8; ++j) {
                const int k = ks * 32 + q * 8 + j;
                u1[j] = f2bf(w1[k * 64 + mt * 16 + c]);
                u2[j] = f2bf(w2[k * 64 + mt * 16 + c]);
            }
            a1[mt][ks] = __builtin_bit_cast(bf16x8, u1);
            a2[mt][ks] = __builtin_bit_cast(bf16x8, u2);
        }
#pragma unroll
    for (int mt = 0; mt < 2; ++mt)
#pragma unroll
        for (int ks = 0; ks < 2; ++ks) {
            ushort8 u3;
#pragma unroll
            for (int j = 0; j < 8; ++j) {
                const int k = ks * 32 + q * 8 + j;
                u3[j] = f2bf(hw[k * 32 + mt * 16 + c]);
            }
            a3[mt][ks] = __builtin_bit_cast(bf16x8, u3);
        }
    f32x4 b1v[4], b2v[4], hbv[2];
#pragma unroll
    for (int mt = 0; mt < 4; ++mt) {
        b1v[mt] = *(const f32x4*)(b1 + mt * 16 + q * 4);
        b2v[mt] = *(const f32x4*)(b2 + mt * 16 + q * 4);
    }
#pragma unroll
    for (int mt = 0; mt < 2; ++mt)
        hbv[mt] = *(const f32x4*)(hbp + mt * 16 + q * 4);

    const int ntiles = N_NODES / 16;
    for (int tile = gwave; tile < ntiles; tile += nwaves) {
        const int n0 = tile * 16;
        const unsigned short* xr = xbf + (size_t)(n0 + c) * 64;
        const float* ar = agg + (size_t)(n0 + c) * 64;

        bf16x8 hb[2];
#pragma unroll
        for (int ks = 0; ks < 2; ++ks) {
            const int o = ks * 32 + q * 8;
            const int b0 = o >> 2, b1i = b0 + 1;
            const int pb0 = (b0 & 3) * 16 + (b0 >> 2) * 4;
            const int pb1 = (b1i & 3) * 16 + (b1i >> 2) * 4;
            const u16x4 xa4 = *(const u16x4*)(xr + pb0);
            const u16x4 xb4 = *(const u16x4*)(xr + pb1);
            const f32x4 aa = *(const f32x4*)(ar + pb0);
            const f32x4 ab = *(const f32x4*)(ar + pb1);
            ushort8 u;
#pragma unroll
            for (int i = 0; i < 4; ++i) {
                u[i]     = f2bf(bf2f(xa4[i]) + aa[i]);
                u[4 + i] = f2bf(bf2f(xb4[i]) + ab[i]);
            }
            hb[ks] = __builtin_bit_cast(bf16x8, u);
        }

        f32x4 acc[4];
#pragma unroll
        for (int mt = 0; mt < 4; ++mt) {
            acc[mt] = __builtin_amdgcn_mfma_f32_16x16x32_bf16(
                a1[mt][0], hb[0], (f32x4){0.f, 0.f, 0.f, 0.f}, 0, 0, 0);
            acc[mt] = __builtin_amdgcn_mfma_f32_16x16x32_bf16(
                a1[mt][1], hb[1], acc[mt], 0, 0, 0);
        }

#pragma unroll
        for (int mt = 0; mt < 4; ++mt) {
            f32x4 t;
#pragma unroll
            for (int r = 0; r < 4; ++r) t[r] = fmaxf(acc[mt][r] + b1v[mt][r], 0.f);
            *(f32x4*)(L + c * LSTRIDE + mt * 16 + q * 4) = t;
        }
        asm volatile("s_waitcnt lgkmcnt(0)" ::: "memory");

        bf16x8 tb[2];
#pragma unroll
        for (int ks = 0; ks < 2; ++ks) {
            const f32x4 lo = *(const f32x4*)(L + c * LSTRIDE + ks * 32 + q * 8);
            const f32x4 hi = *(const f32x4*)(L + c * LSTRIDE + ks * 32 + q * 8 + 4);
            ushort8 u;
            u[0] = f2bf(lo[0]); u[1] = f2bf(lo[1]); u[2] = f2bf(lo[2]); u[3] = f2bf(lo[3]);
            u[4] = f2bf(hi[0]); u[5] = f2bf(hi[1]); u[6] = f2bf(hi[2]); u[7] = f2bf(hi[3]);
            tb[ks] = __builtin_bit_cast(bf16x8, u);
        }
        asm volatile("s_waitcnt lgkmcnt(0)" ::: "memory");

#pragma unroll
        for (int mt = 0; mt < 4; ++mt) {
            acc[mt] = __builtin_amdgcn_mfma_f32_16x16x32_bf16(
                a2[mt][0], tb[0], (f32x4){0.f, 0.f, 0.f, 0.f}, 0, 0, 0);
            acc[mt] = __builtin_amdgcn_mfma_f32_16x16x32_bf16(
                a2[mt][1], tb[1], acc[mt], 0, 0, 0);
        }

#pragma unroll
        for (int mt = 0; mt < 4; ++mt) {
            f32x4 t;
#pragma unroll
            for (int r = 0; r < 4; ++r) t[r] = fmaxf(acc[mt][r] + b2v[mt][r], 0.f);
            *(f32x4*)(L + c * LSTRIDE + mt * 16 + q * 4) = t;
        }
        asm volatile("s_waitcnt lgkmcnt(0)" ::: "memory");

        bf16x8 ub[2];
#pragma unroll
        for (int ks = 0; ks < 2; ++ks) {
            const f32x4 lo = *(const f32x4*)(L + c * LSTRIDE + ks * 32 + q * 8);
            const f32x4 hi = *(const f32x4*)(L + c * LSTRIDE + ks * 32 + q * 8 + 4);
            ushort8 u;
            u[0] = f2bf(lo[0]); u[1] = f2bf(lo[1]); u[2] = f2bf(lo[2]); u[3] = f2bf(lo[3]);
            u[4] = f2bf(hi[0]); u[5] = f2bf(hi[1]); u[6] = f2bf(hi[2]); u[7] = f2bf(hi[3]);
            ub[ks] = __builtin_bit_cast(bf16x8, u);
        }
        asm volatile("s_waitcnt lgkmcnt(0)" ::: "memory");

        f32x4 acc3[2];
#pragma unroll
        for (int mt = 0; mt < 2; ++mt) {
            acc3[mt] = __builtin_amdgcn_mfma_f32_16x16x32_bf16(
                a3[mt][0], ub[0], (f32x4){0.f, 0.f, 0.f, 0.f}, 0, 0, 0);
            acc3[mt] = __builtin_amdgcn_mfma_f32_16x16x32_bf16(
                a3[mt][1], ub[1], acc3[mt], 0, 0, 0);
        }

        float* outr = outp + (size_t)(n0 + c) * 32;
#pragma unroll
        for (int mt = 0; mt < 2; ++mt) {
            f32x4 u;
#pragma unroll
            for (int r = 0; r < 4; ++r) u[r] = acc3[mt][r] + hbv[mt][r];
            *(f32x4*)(outr + mt * 16 + q * 4) = u;
        }
    }
}

extern "C" void kernel_launch(void* const* d_in, const int* in_sizes, int n_in,
                              void* d_out, int out_size, void* d_ws, size_t ws_size,
                              hipStream_t stream) {
    const float* x     = (const float*)d_in[0];
    const float* ea    = (const float*)d_in[1];
    const int*   ei    = (const int*)  d_in[2];
    const float* c1lw  = (const float*)d_in[3];
    const float* c1lb  = (const float*)d_in[4];
    const float* c1w1  = (const float*)d_in[5];
    const float* c1b1  = (const float*)d_in[6];
    const float* c1w2  = (const float*)d_in[7];
    const float* c1b2  = (const float*)d_in[8];
    const float* c2lw  = (const float*)d_in[9];
    const float* c2lb  = (const float*)d_in[10];
    const float* c2w1  = (const float*)d_in[11];
    const float* c2b1  = (const float*)d_in[12];
    const float* c2w2  = (const float*)d_in[13];
    const float* c2b2  = (const float*)d_in[14];
    const float* hw    = (const float*)d_in[15];
    const float* hb    = (const float*)d_in[16];

    const int* srcp = ei;
    const int* dstp = ei + N_EDGES;

    float*          agg = (float*)d_ws;                            // [N,64] f32
    unsigned short* xbf = (unsigned short*)(agg + (size_t)N_NODES * 64); // [N,64] bf16
    unsigned short* hbf = xbf + (size_t)N_NODES * 64;              // [N,64] bf16
    int*   cnt  = (int*)(hbf + (size_t)N_NODES * 64);              // [N]
    int*   offs = cnt + N_NODES;                                   // [N+1]
    int*   bsum = offs + (N_NODES + 1);                            // [256]
    int*   bpre = bsum + 256;                                      // [256]
    int*   ssrc = bpre + 256;                                      // [E]
    int*   rank = ssrc + N_EDGES;                                  // [E]
    size_t tail_off = ((size_t)((char*)(rank + N_EDGES) - (char*)d_ws) + 63) & ~(size_t)63;
    unsigned short* ea_s = (unsigned short*)((char*)d_ws + tail_off);   // [E,32] bf16
    int*            perm_tail = (int*)((char*)d_ws + tail_off);         // fallback [E]
    const bool primary = ws_size >= tail_off + (size_t)N_EDGES * 32 * sizeof(unsigned short) + 64;

    // primary: perm aliases hbf (perm dead once node1 writes hbf)
    int* perm = primary ? (int*)hbf : perm_tail;

    float* outp = (float*)d_out;
    const int SCAN_G = (N_NODES + 255) / 256;

    hipMemsetAsync(cnt, 0, N_NODES * sizeof(int), stream);
    hipLaunchKernelGGL(csr_hist_rank, dim3(2048), dim3(256), 0, stream, dstp, cnt, rank);
    hipLaunchKernelGGL(scan_p1, dim3(256),    dim3(256), 0, stream, cnt, bsum);
    hipLaunchKernelGGL(scan_p2, dim3(1),      dim3(256), 0, stream, bsum, bpre, offs);
    hipLaunchKernelGGL(scan_p3, dim3(SCAN_G), dim3(256), 0, stream, cnt, bpre, offs);
    hipLaunchKernelGGL(csr_scatter_perm_rank, dim3(2048), dim3(256), 0, stream,
                       dstp, rank, offs, perm);
    hipLaunchKernelGGL(x_to_bf, dim3(512), dim3(256), 0, stream, x, xbf);

    if (primary) {
        hipLaunchKernelGGL(csr_permute_ea, dim3(4096), dim3(256), 0, stream,
                           ea, srcp, perm, ssrc, ea_s);
        hipLaunchKernelGGL(gine_gather_bf, dim3(4096), dim3(256), 0, stream,
                           xbf, ea_s, ssrc, offs, c1lw, c1lb, agg);
        hipLaunchKernelGGL(gine_node_mfma, dim3(800), dim3(256), 0, stream,
                           x, agg, c1w1, c1b1, c1w2, c1b2, hbf);
        hipLaunchKernelGGL(gine_gather_bf, dim3(4096), dim3(256), 0, stream,
                           hbf, ea_s, ssrc, offs, c2lw, c2lb, agg);
        hipLaunchKernelGGL(gine_node_head_mfma, dim3(800), dim3(256), 0, stream,
                           hbf, agg, c2w1, c2b1, c2w2, c2b2, hw, hb, outp);
    } else {
        // fallback: ssrc from perm gather (one kernel reused: permute w/o ea_s
        // not available — derive ssrc inline in gather via perm+srcp instead)
        hipLaunchKernelGGL(csr_permute_ea, dim3(4096), dim3(256), 0, stream,
                           ea, srcp, perm, ssrc, (unsigned short*)hbf /*scratch, unused rows*/);
        hipLaunchKernelGGL(gine_gather_fb, dim3(4096), dim3(256), 0, stream,
                           xbf, ea, perm, ssrc, offs, c1lw, c1lb, agg);
        hipLaunchKernelGGL(gine_node_mfma, dim3(800), dim3(256), 0, stream,
                           x, agg, c1w1, c1b1, c1w2, c1b2, hbf);
        hipLaunchKernelGGL(gine_gather_fb, dim3(4096), dim3(256), 0, stream,
                           hbf, ea, perm, ssrc, offs, c2lw, c2lb, agg);
        hipLaunchKernelGGL(gine_node_head_mfma, dim3(800), dim3(256), 0, stream,
                           hbf, agg, c2w1, c2b1, c2w2, c2b2, hw, hb, outp);
    }
}